// Round 1
// baseline (1921.853 us; speedup 1.0000x reference)
//
#include <hip/hip_runtime.h>
#include <cstdint>
#include <cstddef>

#define NN 50000
#define NE 800000
#define HID 256
#define TDIM 128

#define BM 64
#define BN 128
#define BK 32

// ---------------- degree / norm ----------------
__global__ __launch_bounds__(256) void deg_kernel(const int* __restrict__ src,
                                                  const int* __restrict__ dst,
                                                  float* __restrict__ od,
                                                  float* __restrict__ idg) {
  int i = blockIdx.x * 256 + threadIdx.x;
  if (i < NE) {
    atomicAdd(&od[src[i]], 1.0f);
    atomicAdd(&idg[dst[i]], 1.0f);
  }
}

__global__ __launch_bounds__(256) void norm_kernel(float* __restrict__ od,
                                                   float* __restrict__ idg) {
  int i = blockIdx.x * 256 + threadIdx.x;
  if (i < NN) {
    od[i]  = 1.0f / sqrtf(fmaxf(od[i], 1.0f));
    idg[i] = 1.0f / sqrtf(fmaxf(idg[i], 1.0f));
  }
}

// ---------------- weight prep ----------------
// W1T[n*256+k] = W1[k*256+n]  (so all GEMMs are NT: C = A * B^T, B rows contiguous in K)
__global__ __launch_bounds__(256) void transpose2(const float* __restrict__ W1,
                                                  const float* __restrict__ W2,
                                                  float* __restrict__ W1T,
                                                  float* __restrict__ W2T) {
  int n = blockIdx.x, k = threadIdx.x;
  W1T[n * 256 + k] = W1[k * 256 + n];
  W2T[n * 256 + k] = W2[k * 256 + n];
}

// Wg rows (per unit u): 4u+0 = Wih_r[u,:256]+Whh_r[u]; 4u+1 = Wih_z+Whh_z; 4u+2 = Wih_n[:256]; 4u+3 = Whh_n
__global__ __launch_bounds__(256) void build_wg(const float* __restrict__ W_ih,
                                                const float* __restrict__ W_hh,
                                                float* __restrict__ Wg) {
  int u = blockIdx.x, k = threadIdx.x;
  Wg[(size_t)(4 * u + 0) * 256 + k] = W_ih[(size_t)u * 384 + k] + W_hh[(size_t)u * 256 + k];
  Wg[(size_t)(4 * u + 1) * 256 + k] = W_ih[(size_t)(256 + u) * 384 + k] + W_hh[(size_t)(256 + u) * 256 + k];
  Wg[(size_t)(4 * u + 2) * 256 + k] = W_ih[(size_t)(512 + u) * 384 + k];
  Wg[(size_t)(4 * u + 3) * 256 + k] = W_hh[(size_t)(512 + u) * 256 + k];
}

// cst[u]=cR, cst[256+u]=cZ, cst[512+u]=cI (i_n const part), cst[768+u]=cH (=b_hh_n)
__global__ __launch_bounds__(256) void build_consts(const float* __restrict__ t,
                                                    const float* __restrict__ tw,
                                                    const float* __restrict__ tb,
                                                    const float* __restrict__ W_ih,
                                                    const float* __restrict__ b_ih,
                                                    const float* __restrict__ b_hh,
                                                    float* __restrict__ cst) {
  __shared__ float te[TDIM];
  int u = threadIdx.x;
  if (u < TDIM) te[u] = cosf(t[0] * tw[u] + tb[u]);
  __syncthreads();
  float cr = b_ih[u] + b_hh[u];
  float cz = b_ih[256 + u] + b_hh[256 + u];
  float ci = b_ih[512 + u];
  for (int k = 0; k < TDIM; ++k) {
    float tk = te[k];
    cr = fmaf(tk, W_ih[(size_t)u * 384 + 256 + k], cr);
    cz = fmaf(tk, W_ih[(size_t)(256 + u) * 384 + 256 + k], cz);
    ci = fmaf(tk, W_ih[(size_t)(512 + u) * 384 + 256 + k], ci);
  }
  cst[u] = cr;
  cst[256 + u] = cz;
  cst[512 + u] = ci;
  cst[768 + u] = b_hh[512 + u];
}

// ---------------- edge aggregation: agg[dst] += x[src] * out_norm[src] ----------------
__global__ __launch_bounds__(256) void scatter_agg(const float* __restrict__ x,
                                                   const int* __restrict__ src,
                                                   const int* __restrict__ dst,
                                                   const float* __restrict__ onorm,
                                                   float* __restrict__ agg) {
  const int f = threadIdx.x;
  const int e0 = blockIdx.x * 8;
#pragma unroll
  for (int j = 0; j < 8; ++j) {
    int e = e0 + j;
    int s = src[e];
    int d = dst[e];
    float v = x[(size_t)s * HID + f] * onorm[s];
    atomicAdd(&agg[(size_t)d * HID + f], v);
  }
}

// ---------------- NT GEMM: C = (scale .* A) * Bt^T, fused epilogue ----------------
// GCN=true : C[row, col] = relu(acc + bias[col]),  Ncols=256 (grid.y=2)
// GCN=false: GRU epilogue, col space = 4*unit+gate, Ncols=1024 (grid.y=8), writes final output
template <bool GCN>
__global__ __launch_bounds__(256) void gemm_nt(const float* __restrict__ A,
                                               const float* __restrict__ scale,
                                               const float* __restrict__ Bt,
                                               const float* __restrict__ bias,
                                               const float* __restrict__ cst,
                                               float* __restrict__ C) {
  __shared__ float As[BK][BM];
  __shared__ float Bs[BK][BN];
  const int row0 = blockIdx.x * BM;
  const int col0 = blockIdx.y * BN;
  const int tid = threadIdx.x;
  const int tx = tid & 15;   // 16 col-groups
  const int ty = tid >> 4;   // 16 row-groups (4 rows each)
  float acc[4][8];
#pragma unroll
  for (int i = 0; i < 4; ++i)
#pragma unroll
    for (int j = 0; j < 8; ++j) acc[i][j] = 0.0f;

  const int ar = tid >> 3;         // 0..31 rows, x2
  const int ak = (tid & 7) << 2;   // k offset, float4
  const int bc = tid >> 1;         // 0..127 cols
  const int bk = (tid & 1) << 4;   // k offset, 4x float4

  for (int k0 = 0; k0 < HID; k0 += BK) {
#pragma unroll
    for (int r = 0; r < 2; ++r) {
      int row = row0 + ar + r * 32;
      int rr = row < NN ? row : NN - 1;
      float4 v = *(const float4*)(A + (size_t)rr * HID + k0 + ak);
      float s = GCN ? scale[rr] : 1.0f;
      As[ak + 0][ar + r * 32] = v.x * s;
      As[ak + 1][ar + r * 32] = v.y * s;
      As[ak + 2][ar + r * 32] = v.z * s;
      As[ak + 3][ar + r * 32] = v.w * s;
    }
#pragma unroll
    for (int q = 0; q < 4; ++q) {
      float4 v = *(const float4*)(Bt + (size_t)(col0 + bc) * HID + k0 + bk + q * 4);
      Bs[bk + q * 4 + 0][bc] = v.x;
      Bs[bk + q * 4 + 1][bc] = v.y;
      Bs[bk + q * 4 + 2][bc] = v.z;
      Bs[bk + q * 4 + 3][bc] = v.w;
    }
    __syncthreads();
#pragma unroll
    for (int kk = 0; kk < BK; ++kk) {
      float4 av = *(const float4*)&As[kk][ty * 4];
      float4 b0 = *(const float4*)&Bs[kk][tx * 4];
      float4 b1 = *(const float4*)&Bs[kk][64 + tx * 4];
      float a[4] = {av.x, av.y, av.z, av.w};
      float b[8] = {b0.x, b0.y, b0.z, b0.w, b1.x, b1.y, b1.z, b1.w};
#pragma unroll
      for (int i = 0; i < 4; ++i)
#pragma unroll
        for (int j = 0; j < 8; ++j) acc[i][j] = fmaf(a[i], b[j], acc[i][j]);
    }
    __syncthreads();
  }

  if (GCN) {
#pragma unroll
    for (int i = 0; i < 4; ++i) {
      int row = row0 + ty * 4 + i;
      if (row < NN) {
        int c0 = col0 + tx * 4;
        float4 o0, o1;
        o0.x = fmaxf(acc[i][0] + bias[c0 + 0], 0.0f);
        o0.y = fmaxf(acc[i][1] + bias[c0 + 1], 0.0f);
        o0.z = fmaxf(acc[i][2] + bias[c0 + 2], 0.0f);
        o0.w = fmaxf(acc[i][3] + bias[c0 + 3], 0.0f);
        o1.x = fmaxf(acc[i][4] + bias[c0 + 64], 0.0f);
        o1.y = fmaxf(acc[i][5] + bias[c0 + 65], 0.0f);
        o1.z = fmaxf(acc[i][6] + bias[c0 + 66], 0.0f);
        o1.w = fmaxf(acc[i][7] + bias[c0 + 67], 0.0f);
        *(float4*)(C + (size_t)row * HID + c0) = o0;
        *(float4*)(C + (size_t)row * HID + c0 + 64) = o1;
      }
    }
  } else {
    const float* cR = cst;
    const float* cZ = cst + 256;
    const float* cI = cst + 512;
    const float* cH = cst + 768;
#pragma unroll
    for (int i = 0; i < 4; ++i) {
      int row = row0 + ty * 4 + i;
      if (row < NN) {
#pragma unroll
        for (int g = 0; g < 2; ++g) {
          int u = (col0 >> 2) + (g ? 16 : 0) + tx;
          float dr = acc[i][g * 4 + 0] + cR[u];
          float dz = acc[i][g * 4 + 1] + cZ[u];
          float dn = acc[i][g * 4 + 2] + cI[u];
          float dh = acc[i][g * 4 + 3] + cH[u];
          float rg = 1.0f / (1.0f + expf(-dr));
          float zg = 1.0f / (1.0f + expf(-dz));
          float ng = tanhf(dn + rg * dh);
          float hv = A[(size_t)row * HID + u];
          C[(size_t)row * HID + u] = (1.0f - zg) * ng + zg * hv;
        }
      }
    }
  }
}

extern "C" void kernel_launch(void* const* d_in, const int* in_sizes, int n_in,
                              void* d_out, int out_size, void* d_ws, size_t ws_size,
                              hipStream_t stream) {
  const float* hidden = (const float*)d_in[0];
  const float* t      = (const float*)d_in[1];
  const int*   src    = (const int*)d_in[2];
  const int*   dst    = (const int*)d_in[3];
  const float* W1     = (const float*)d_in[4];
  const float* b1     = (const float*)d_in[5];
  const float* W2     = (const float*)d_in[6];
  const float* b2     = (const float*)d_in[7];
  const float* time_w = (const float*)d_in[8];
  const float* time_b = (const float*)d_in[9];
  const float* W_ih   = (const float*)d_in[10];
  const float* W_hh   = (const float*)d_in[11];
  const float* b_ih   = (const float*)d_in[12];
  const float* b_hh   = (const float*)d_in[13];
  float* out = (float*)d_out;

  float* W = (float*)d_ws;
  float* onorm = W;                                   // 50048
  float* inorm = W + 50048;                           // 50048
  float* agg   = W + 100096;                          // NN*HID
  float* h     = agg + (size_t)NN * HID;              // NN*HID
  float* W1T   = h + (size_t)NN * HID;                // 65536
  float* W2T   = W1T + 65536;                         // 65536
  float* Wg    = W2T + 65536;                         // 262144
  float* cst   = Wg + 262144;                         // 1024

  // degrees -> norms
  hipMemsetAsync(onorm, 0, 100096 * sizeof(float), stream);
  deg_kernel<<<NE / 256, 256, 0, stream>>>(src, dst, onorm, inorm);
  norm_kernel<<<(NN + 255) / 256, 256, 0, stream>>>(onorm, inorm);

  // weight prep (independent of graph data ordering)
  transpose2<<<256, 256, 0, stream>>>(W1, W2, W1T, W2T);
  build_wg<<<256, 256, 0, stream>>>(W_ih, W_hh, Wg);
  build_consts<<<1, 256, 0, stream>>>(t, time_w, time_b, W_ih, b_ih, b_hh, cst);

  dim3 gGcn((NN + BM - 1) / BM, 2);
  dim3 gGru((NN + BM - 1) / BM, 8);

  // layer 1
  hipMemsetAsync(agg, 0, (size_t)NN * HID * sizeof(float), stream);
  scatter_agg<<<NE / 8, 256, 0, stream>>>(hidden, src, dst, onorm, agg);
  gemm_nt<true><<<gGcn, 256, 0, stream>>>(agg, inorm, W1T, b1, nullptr, h);

  // layer 2 (ref applies relu(h) after the no-relu layer -> same as relu epilogue)
  hipMemsetAsync(agg, 0, (size_t)NN * HID * sizeof(float), stream);
  scatter_agg<<<NE / 8, 256, 0, stream>>>(h, src, dst, onorm, agg);
  gemm_nt<true><<<gGcn, 256, 0, stream>>>(agg, inorm, W2T, b2, nullptr, h);

  // GRU: single NT GEMM (K=256, N=1024) with fused gate epilogue -> d_out
  gemm_nt<false><<<gGru, 256, 0, stream>>>(h, nullptr, Wg, nullptr, cst, out);
}

// Round 2
// 965.181 us; speedup vs baseline: 1.9912x; 1.9912x over previous
//
#include <hip/hip_runtime.h>
#include <cstdint>
#include <cstddef>

#define NN 50000
#define NE 800000
#define HID 256
#define TDIM 128

#define BM 64
#define BN 128
#define BK 32

// ---------------- degree count ----------------
__global__ __launch_bounds__(256) void deg_kernel(const int* __restrict__ src,
                                                  const int* __restrict__ dst,
                                                  float* __restrict__ od,
                                                  float* __restrict__ idg) {
  int i = blockIdx.x * 256 + threadIdx.x;
  if (i < NE) {
    atomicAdd(&od[src[i]], 1.0f);
    atomicAdd(&idg[dst[i]], 1.0f);
  }
}

__global__ __launch_bounds__(256) void norm_kernel(float* __restrict__ od,
                                                   float* __restrict__ idg) {
  int i = blockIdx.x * 256 + threadIdx.x;
  if (i < NN) {
    od[i]  = 1.0f / sqrtf(fmaxf(od[i], 1.0f));
    idg[i] = 1.0f / sqrtf(fmaxf(idg[i], 1.0f));
  }
}

// ---------------- CSR build ----------------
// Exclusive scan of in-degrees (read as float counts BEFORE norm overwrites them).
// Single block, 1024 threads, shfl wave-scan + cross-wave LDS offsets.
__global__ __launch_bounds__(1024) void scan_rows(const float* __restrict__ idg,
                                                  int* __restrict__ rowstart,
                                                  int* __restrict__ cursor) {
  __shared__ int wsum[16];
  __shared__ int carry_s;
  const int tid = threadIdx.x, lane = tid & 63, w = tid >> 6;
  if (tid == 0) { carry_s = 0; rowstart[0] = 0; }
  __syncthreads();
  for (int base = 0; base < NN; base += 1024) {
    int i = base + tid;
    int v = (i < NN) ? (int)idg[i] : 0;
    int inc = v;
#pragma unroll
    for (int off = 1; off < 64; off <<= 1) {
      int t = __shfl_up(inc, off, 64);
      if (lane >= off) inc += t;
    }
    if (lane == 63) wsum[w] = inc;
    __syncthreads();
    int woff = 0;
    for (int k = 0; k < w; ++k) woff += wsum[k];
    int carry = carry_s;
    int excl = carry + woff + inc - v;
    if (i < NN) { rowstart[i + 1] = excl + v; cursor[i] = excl; }
    __syncthreads();
    if (tid == 1023) carry_s = carry + woff + inc;
    __syncthreads();
  }
}

__global__ __launch_bounds__(256) void fill_csr(const int* __restrict__ src,
                                                const int* __restrict__ dst,
                                                int* __restrict__ cursor,
                                                int* __restrict__ col) {
  int e = blockIdx.x * 256 + threadIdx.x;
  if (e < NE) {
    int d = dst[e];
    int pos = atomicAdd(&cursor[d], 1);
    col[pos] = src[e];
  }
}

// ---------------- gather aggregation: agg[n] = inorm[n] * sum_{e in CSR row n} onorm[src] * x[src]
// one wave per node; each lane owns a float4 feature slice (64*4 = 256)
__global__ __launch_bounds__(256) void gather_agg(const float* __restrict__ x,
                                                  const int* __restrict__ rowstart,
                                                  const int* __restrict__ col,
                                                  const float* __restrict__ onorm,
                                                  const float* __restrict__ inorm,
                                                  float* __restrict__ agg) {
  const int wid = blockIdx.x * 4 + (threadIdx.x >> 6);
  const int lane = threadIdx.x & 63;
  if (wid >= NN) return;
  const int e1 = rowstart[wid + 1];
  int e = rowstart[wid];
  const int fo = lane * 4;
  float4 a0 = make_float4(0.f, 0.f, 0.f, 0.f);
  float4 a1 = make_float4(0.f, 0.f, 0.f, 0.f);
  for (; e + 2 <= e1; e += 2) {
    int s0 = col[e], s1 = col[e + 1];
    float w0 = onorm[s0], w1 = onorm[s1];
    float4 v0 = *(const float4*)(x + (size_t)s0 * HID + fo);
    float4 v1 = *(const float4*)(x + (size_t)s1 * HID + fo);
    a0.x = fmaf(v0.x, w0, a0.x); a0.y = fmaf(v0.y, w0, a0.y);
    a0.z = fmaf(v0.z, w0, a0.z); a0.w = fmaf(v0.w, w0, a0.w);
    a1.x = fmaf(v1.x, w1, a1.x); a1.y = fmaf(v1.y, w1, a1.y);
    a1.z = fmaf(v1.z, w1, a1.z); a1.w = fmaf(v1.w, w1, a1.w);
  }
  if (e < e1) {
    int s0 = col[e];
    float w0 = onorm[s0];
    float4 v0 = *(const float4*)(x + (size_t)s0 * HID + fo);
    a0.x = fmaf(v0.x, w0, a0.x); a0.y = fmaf(v0.y, w0, a0.y);
    a0.z = fmaf(v0.z, w0, a0.z); a0.w = fmaf(v0.w, w0, a0.w);
  }
  const float wi = inorm[wid];
  float4 r;
  r.x = (a0.x + a1.x) * wi;
  r.y = (a0.y + a1.y) * wi;
  r.z = (a0.z + a1.z) * wi;
  r.w = (a0.w + a1.w) * wi;
  *(float4*)(agg + (size_t)wid * HID + fo) = r;
}

// ---------------- weight prep ----------------
__global__ __launch_bounds__(256) void transpose2(const float* __restrict__ W1,
                                                  const float* __restrict__ W2,
                                                  float* __restrict__ W1T,
                                                  float* __restrict__ W2T) {
  int n = blockIdx.x, k = threadIdx.x;
  W1T[n * 256 + k] = W1[k * 256 + n];
  W2T[n * 256 + k] = W2[k * 256 + n];
}

__global__ __launch_bounds__(256) void build_wg(const float* __restrict__ W_ih,
                                                const float* __restrict__ W_hh,
                                                float* __restrict__ Wg) {
  int u = blockIdx.x, k = threadIdx.x;
  Wg[(size_t)(4 * u + 0) * 256 + k] = W_ih[(size_t)u * 384 + k] + W_hh[(size_t)u * 256 + k];
  Wg[(size_t)(4 * u + 1) * 256 + k] = W_ih[(size_t)(256 + u) * 384 + k] + W_hh[(size_t)(256 + u) * 256 + k];
  Wg[(size_t)(4 * u + 2) * 256 + k] = W_ih[(size_t)(512 + u) * 384 + k];
  Wg[(size_t)(4 * u + 3) * 256 + k] = W_hh[(size_t)(512 + u) * 256 + k];
}

__global__ __launch_bounds__(256) void build_consts(const float* __restrict__ t,
                                                    const float* __restrict__ tw,
                                                    const float* __restrict__ tb,
                                                    const float* __restrict__ W_ih,
                                                    const float* __restrict__ b_ih,
                                                    const float* __restrict__ b_hh,
                                                    float* __restrict__ cst) {
  __shared__ float te[TDIM];
  int u = threadIdx.x;
  if (u < TDIM) te[u] = cosf(t[0] * tw[u] + tb[u]);
  __syncthreads();
  float cr = b_ih[u] + b_hh[u];
  float cz = b_ih[256 + u] + b_hh[256 + u];
  float ci = b_ih[512 + u];
  for (int k = 0; k < TDIM; ++k) {
    float tk = te[k];
    cr = fmaf(tk, W_ih[(size_t)u * 384 + 256 + k], cr);
    cz = fmaf(tk, W_ih[(size_t)(256 + u) * 384 + 256 + k], cz);
    ci = fmaf(tk, W_ih[(size_t)(512 + u) * 384 + 256 + k], ci);
  }
  cst[u] = cr;
  cst[256 + u] = cz;
  cst[512 + u] = ci;
  cst[768 + u] = b_hh[512 + u];
}

// ---------------- NT GEMM: C = A * Bt^T, fused epilogue ----------------
template <bool GCN>
__global__ __launch_bounds__(256) void gemm_nt(const float* __restrict__ A,
                                               const float* __restrict__ Bt,
                                               const float* __restrict__ bias,
                                               const float* __restrict__ cst,
                                               float* __restrict__ C) {
  __shared__ float As[BK][BM];
  __shared__ float Bs[BK][BN];
  const int row0 = blockIdx.x * BM;
  const int col0 = blockIdx.y * BN;
  const int tid = threadIdx.x;
  const int tx = tid & 15;
  const int ty = tid >> 4;
  float acc[4][8];
#pragma unroll
  for (int i = 0; i < 4; ++i)
#pragma unroll
    for (int j = 0; j < 8; ++j) acc[i][j] = 0.0f;

  const int ar = tid >> 3;
  const int ak = (tid & 7) << 2;
  const int bc = tid >> 1;
  const int bk = (tid & 1) << 4;

  for (int k0 = 0; k0 < HID; k0 += BK) {
#pragma unroll
    for (int r = 0; r < 2; ++r) {
      int row = row0 + ar + r * 32;
      int rr = row < NN ? row : NN - 1;
      float4 v = *(const float4*)(A + (size_t)rr * HID + k0 + ak);
      As[ak + 0][ar + r * 32] = v.x;
      As[ak + 1][ar + r * 32] = v.y;
      As[ak + 2][ar + r * 32] = v.z;
      As[ak + 3][ar + r * 32] = v.w;
    }
#pragma unroll
    for (int q = 0; q < 4; ++q) {
      float4 v = *(const float4*)(Bt + (size_t)(col0 + bc) * HID + k0 + bk + q * 4);
      Bs[bk + q * 4 + 0][bc] = v.x;
      Bs[bk + q * 4 + 1][bc] = v.y;
      Bs[bk + q * 4 + 2][bc] = v.z;
      Bs[bk + q * 4 + 3][bc] = v.w;
    }
    __syncthreads();
#pragma unroll
    for (int kk = 0; kk < BK; ++kk) {
      float4 av = *(const float4*)&As[kk][ty * 4];
      float4 b0 = *(const float4*)&Bs[kk][tx * 4];
      float4 b1 = *(const float4*)&Bs[kk][64 + tx * 4];
      float a[4] = {av.x, av.y, av.z, av.w};
      float b[8] = {b0.x, b0.y, b0.z, b0.w, b1.x, b1.y, b1.z, b1.w};
#pragma unroll
      for (int i = 0; i < 4; ++i)
#pragma unroll
        for (int j = 0; j < 8; ++j) acc[i][j] = fmaf(a[i], b[j], acc[i][j]);
    }
    __syncthreads();
  }

  if (GCN) {
#pragma unroll
    for (int i = 0; i < 4; ++i) {
      int row = row0 + ty * 4 + i;
      if (row < NN) {
        int c0 = col0 + tx * 4;
        float4 o0, o1;
        o0.x = fmaxf(acc[i][0] + bias[c0 + 0], 0.0f);
        o0.y = fmaxf(acc[i][1] + bias[c0 + 1], 0.0f);
        o0.z = fmaxf(acc[i][2] + bias[c0 + 2], 0.0f);
        o0.w = fmaxf(acc[i][3] + bias[c0 + 3], 0.0f);
        o1.x = fmaxf(acc[i][4] + bias[c0 + 64], 0.0f);
        o1.y = fmaxf(acc[i][5] + bias[c0 + 65], 0.0f);
        o1.z = fmaxf(acc[i][6] + bias[c0 + 66], 0.0f);
        o1.w = fmaxf(acc[i][7] + bias[c0 + 67], 0.0f);
        *(float4*)(C + (size_t)row * HID + c0) = o0;
        *(float4*)(C + (size_t)row * HID + c0 + 64) = o1;
      }
    }
  } else {
    const float* cR = cst;
    const float* cZ = cst + 256;
    const float* cI = cst + 512;
    const float* cH = cst + 768;
#pragma unroll
    for (int i = 0; i < 4; ++i) {
      int row = row0 + ty * 4 + i;
      if (row < NN) {
#pragma unroll
        for (int g = 0; g < 2; ++g) {
          int u = (col0 >> 2) + (g ? 16 : 0) + tx;
          float dr = acc[i][g * 4 + 0] + cR[u];
          float dz = acc[i][g * 4 + 1] + cZ[u];
          float dn = acc[i][g * 4 + 2] + cI[u];
          float dh = acc[i][g * 4 + 3] + cH[u];
          float rg = 1.0f / (1.0f + expf(-dr));
          float zg = 1.0f / (1.0f + expf(-dz));
          float ng = tanhf(dn + rg * dh);
          float hv = A[(size_t)row * HID + u];
          C[(size_t)row * HID + u] = (1.0f - zg) * ng + zg * hv;
        }
      }
    }
  }
}

extern "C" void kernel_launch(void* const* d_in, const int* in_sizes, int n_in,
                              void* d_out, int out_size, void* d_ws, size_t ws_size,
                              hipStream_t stream) {
  const float* hidden = (const float*)d_in[0];
  const float* t      = (const float*)d_in[1];
  const int*   src    = (const int*)d_in[2];
  const int*   dst    = (const int*)d_in[3];
  const float* W1     = (const float*)d_in[4];
  const float* b1     = (const float*)d_in[5];
  const float* W2     = (const float*)d_in[6];
  const float* b2     = (const float*)d_in[7];
  const float* time_w = (const float*)d_in[8];
  const float* time_b = (const float*)d_in[9];
  const float* W_ih   = (const float*)d_in[10];
  const float* W_hh   = (const float*)d_in[11];
  const float* b_ih   = (const float*)d_in[12];
  const float* b_hh   = (const float*)d_in[13];
  float* out = (float*)d_out;

  float* W = (float*)d_ws;
  float* onorm = W;                                   // 50048
  float* inorm = W + 50048;                           // 50048
  float* agg   = W + 100096;                          // NN*HID
  float* h     = agg + (size_t)NN * HID;              // NN*HID
  float* W1T   = h + (size_t)NN * HID;                // 65536
  float* W2T   = W1T + 65536;                         // 65536
  float* Wg    = W2T + 65536;                         // 262144
  float* cst   = Wg + 262144;                         // 1024
  int* rowstart = (int*)(cst + 1024);                 // NN+1 (pad to 50052)
  int* cursor   = rowstart + 50052;                   // NN
  int* col      = cursor + 50048;                     // NE

  // degrees -> CSR scan -> norms
  hipMemsetAsync(onorm, 0, 100096 * sizeof(float), stream);
  deg_kernel<<<NE / 256, 256, 0, stream>>>(src, dst, onorm, inorm);
  scan_rows<<<1, 1024, 0, stream>>>(inorm, rowstart, cursor);   // reads raw counts
  norm_kernel<<<(NN + 255) / 256, 256, 0, stream>>>(onorm, inorm);
  fill_csr<<<(NE + 255) / 256, 256, 0, stream>>>(src, dst, cursor, col);

  // weight prep
  transpose2<<<256, 256, 0, stream>>>(W1, W2, W1T, W2T);
  build_wg<<<256, 256, 0, stream>>>(W_ih, W_hh, Wg);
  build_consts<<<1, 256, 0, stream>>>(t, time_w, time_b, W_ih, b_ih, b_hh, cst);

  dim3 gGcn((NN + BM - 1) / BM, 2);
  dim3 gGru((NN + BM - 1) / BM, 8);
  const int gather_blocks = (NN + 3) / 4;

  // layer 1
  gather_agg<<<gather_blocks, 256, 0, stream>>>(hidden, rowstart, col, onorm, inorm, agg);
  gemm_nt<true><<<gGcn, 256, 0, stream>>>(agg, W1T, b1, nullptr, h);

  // layer 2 (relu folded into epilogue; matches ref's post-relu)
  gather_agg<<<gather_blocks, 256, 0, stream>>>(h, rowstart, col, onorm, inorm, agg);
  gemm_nt<true><<<gGcn, 256, 0, stream>>>(agg, W2T, b2, nullptr, h);

  // GRU: single NT GEMM (K=256, Ncols=1024) with fused gate epilogue -> d_out
  gemm_nt<false><<<gGru, 256, 0, stream>>>(h, Wg, nullptr, cst, out);
}

// Round 3
// 730.250 us; speedup vs baseline: 2.6318x; 1.3217x over previous
//
#include <hip/hip_runtime.h>
#include <cstdint>
#include <cstddef>

#define NN 50000
#define NE 800000
#define HID 256
#define TDIM 128

typedef short bf16x8 __attribute__((ext_vector_type(8)));
typedef float f32x4 __attribute__((ext_vector_type(4)));

__device__ inline unsigned short f2bf(float f) {
  uint32_t u = __builtin_bit_cast(uint32_t, f);
  uint32_t r = u + 0x7FFFu + ((u >> 16) & 1u);
  return (unsigned short)(r >> 16);
}
__device__ inline float bf2f(unsigned short s) {
  uint32_t u = ((uint32_t)s) << 16;
  return __builtin_bit_cast(float, u);
}

// ---------------- degree / norm ----------------
__global__ __launch_bounds__(256) void deg_kernel(const int* __restrict__ src,
                                                  const int* __restrict__ dst,
                                                  float* __restrict__ od,
                                                  float* __restrict__ idg) {
  int i = blockIdx.x * 256 + threadIdx.x;
  if (i < NE) {
    atomicAdd(&od[src[i]], 1.0f);
    atomicAdd(&idg[dst[i]], 1.0f);
  }
}

__global__ __launch_bounds__(256) void norm_kernel(float* __restrict__ od,
                                                   float* __restrict__ idg) {
  int i = blockIdx.x * 256 + threadIdx.x;
  if (i < NN) {
    od[i]  = 1.0f / sqrtf(fmaxf(od[i], 1.0f));
    idg[i] = 1.0f / sqrtf(fmaxf(idg[i], 1.0f));
  }
}

// ---------------- CSR build ----------------
__global__ __launch_bounds__(1024) void scan_rows(const float* __restrict__ idg,
                                                  int* __restrict__ rowstart,
                                                  int* __restrict__ cursor) {
  __shared__ int wsum[16];
  __shared__ int carry_s;
  const int tid = threadIdx.x, lane = tid & 63, w = tid >> 6;
  if (tid == 0) { carry_s = 0; rowstart[0] = 0; }
  __syncthreads();
  for (int base = 0; base < NN; base += 1024) {
    int i = base + tid;
    int v = (i < NN) ? (int)idg[i] : 0;
    int inc = v;
#pragma unroll
    for (int off = 1; off < 64; off <<= 1) {
      int t = __shfl_up(inc, off, 64);
      if (lane >= off) inc += t;
    }
    if (lane == 63) wsum[w] = inc;
    __syncthreads();
    int woff = 0;
    for (int k = 0; k < w; ++k) woff += wsum[k];
    int carry = carry_s;
    int excl = carry + woff + inc - v;
    if (i < NN) { rowstart[i + 1] = excl + v; cursor[i] = excl; }
    __syncthreads();
    if (tid == 1023) carry_s = carry + woff + inc;
    __syncthreads();
  }
}

__global__ __launch_bounds__(256) void fill_csr(const int* __restrict__ src,
                                                const int* __restrict__ dst,
                                                int* __restrict__ cursor,
                                                int* __restrict__ col) {
  int e = blockIdx.x * 256 + threadIdx.x;
  if (e < NE) {
    int d = dst[e];
    int pos = atomicAdd(&cursor[d], 1);
    col[pos] = src[e];
  }
}

// ---------------- gather aggregation -> split bf16 planes ----------------
template <bool BF>
__device__ inline float4 loadx(const float* __restrict__ xf,
                               const short* __restrict__ xH,
                               const short* __restrict__ xL, size_t off) {
  if constexpr (!BF) {
    return *(const float4*)(xf + off);
  } else {
    uint2 uh = *(const uint2*)(xH + off);
    uint2 ul = *(const uint2*)(xL + off);
    float4 r;
    r.x = bf2f((unsigned short)(uh.x & 0xFFFF)) + bf2f((unsigned short)(ul.x & 0xFFFF));
    r.y = bf2f((unsigned short)(uh.x >> 16))    + bf2f((unsigned short)(ul.x >> 16));
    r.z = bf2f((unsigned short)(uh.y & 0xFFFF)) + bf2f((unsigned short)(ul.y & 0xFFFF));
    r.w = bf2f((unsigned short)(uh.y >> 16))    + bf2f((unsigned short)(ul.y >> 16));
    return r;
  }
}

template <bool BF>
__global__ __launch_bounds__(256) void gather_agg(const float* __restrict__ xf,
                                                  const short* __restrict__ xH,
                                                  const short* __restrict__ xL,
                                                  const int* __restrict__ rowstart,
                                                  const int* __restrict__ col,
                                                  const float* __restrict__ onorm,
                                                  const float* __restrict__ inorm,
                                                  short* __restrict__ aggH,
                                                  short* __restrict__ aggL) {
  const int wid = blockIdx.x * 4 + (threadIdx.x >> 6);
  const int lane = threadIdx.x & 63;
  if (wid >= NN) return;
  const int e1 = rowstart[wid + 1];
  int e = rowstart[wid];
  const int fo = lane * 4;
  float a0[4] = {0.f, 0.f, 0.f, 0.f};
  float a1[4] = {0.f, 0.f, 0.f, 0.f};
  for (; e + 2 <= e1; e += 2) {
    int s0 = col[e], s1 = col[e + 1];
    float w0 = onorm[s0], w1 = onorm[s1];
    float4 v0 = loadx<BF>(xf, xH, xL, (size_t)s0 * HID + fo);
    float4 v1 = loadx<BF>(xf, xH, xL, (size_t)s1 * HID + fo);
    a0[0] = fmaf(v0.x, w0, a0[0]); a0[1] = fmaf(v0.y, w0, a0[1]);
    a0[2] = fmaf(v0.z, w0, a0[2]); a0[3] = fmaf(v0.w, w0, a0[3]);
    a1[0] = fmaf(v1.x, w1, a1[0]); a1[1] = fmaf(v1.y, w1, a1[1]);
    a1[2] = fmaf(v1.z, w1, a1[2]); a1[3] = fmaf(v1.w, w1, a1[3]);
  }
  if (e < e1) {
    int s0 = col[e];
    float w0 = onorm[s0];
    float4 v0 = loadx<BF>(xf, xH, xL, (size_t)s0 * HID + fo);
    a0[0] = fmaf(v0.x, w0, a0[0]); a0[1] = fmaf(v0.y, w0, a0[1]);
    a0[2] = fmaf(v0.z, w0, a0[2]); a0[3] = fmaf(v0.w, w0, a0[3]);
  }
  const float wi = inorm[wid];
  float r[4];
  r[0] = (a0[0] + a1[0]) * wi;
  r[1] = (a0[1] + a1[1]) * wi;
  r[2] = (a0[2] + a1[2]) * wi;
  r[3] = (a0[3] + a1[3]) * wi;
  unsigned int hb[2], lb[2];
#pragma unroll
  for (int q = 0; q < 2; ++q) {
    unsigned short h0 = f2bf(r[q * 2 + 0]);
    unsigned short h1 = f2bf(r[q * 2 + 1]);
    unsigned short l0 = f2bf(r[q * 2 + 0] - bf2f(h0));
    unsigned short l1 = f2bf(r[q * 2 + 1] - bf2f(h1));
    hb[q] = (unsigned int)h0 | ((unsigned int)h1 << 16);
    lb[q] = (unsigned int)l0 | ((unsigned int)l1 << 16);
  }
  size_t off = (size_t)wid * HID + fo;
  *(uint2*)(aggH + off) = make_uint2(hb[0], hb[1]);
  *(uint2*)(aggL + off) = make_uint2(lb[0], lb[1]);
}

// ---------------- weight prep: transpose + hi/lo split ----------------
__global__ __launch_bounds__(256) void transpose_split(const float* __restrict__ W1,
                                                       const float* __restrict__ W2,
                                                       short* __restrict__ W1H, short* __restrict__ W1L,
                                                       short* __restrict__ W2H, short* __restrict__ W2L) {
  int n = blockIdx.x, k = threadIdx.x;
  float a = W1[k * 256 + n];
  unsigned short h = f2bf(a);
  W1H[n * 256 + k] = (short)h;
  W1L[n * 256 + k] = (short)f2bf(a - bf2f(h));
  float b = W2[k * 256 + n];
  unsigned short h2 = f2bf(b);
  W2H[n * 256 + k] = (short)h2;
  W2L[n * 256 + k] = (short)f2bf(b - bf2f(h2));
}

// Wg row layout: gate-blocked by 16: row(u,g) = (u>>4)*64 + g*16 + (u&15)
__global__ __launch_bounds__(256) void build_wg(const float* __restrict__ W_ih,
                                                const float* __restrict__ W_hh,
                                                short* __restrict__ WgH,
                                                short* __restrict__ WgL) {
  int u = blockIdx.x, k = threadIdx.x;
  int base = (u >> 4) * 64 + (u & 15);
  float v[4];
  v[0] = W_ih[(size_t)u * 384 + k] + W_hh[(size_t)u * 256 + k];
  v[1] = W_ih[(size_t)(256 + u) * 384 + k] + W_hh[(size_t)(256 + u) * 256 + k];
  v[2] = W_ih[(size_t)(512 + u) * 384 + k];
  v[3] = W_hh[(size_t)(512 + u) * 256 + k];
#pragma unroll
  for (int g = 0; g < 4; ++g) {
    size_t off = (size_t)(base + g * 16) * 256 + k;
    unsigned short h = f2bf(v[g]);
    WgH[off] = (short)h;
    WgL[off] = (short)f2bf(v[g] - bf2f(h));
  }
}

__global__ __launch_bounds__(256) void build_consts(const float* __restrict__ t,
                                                    const float* __restrict__ tw,
                                                    const float* __restrict__ tb,
                                                    const float* __restrict__ W_ih,
                                                    const float* __restrict__ b_ih,
                                                    const float* __restrict__ b_hh,
                                                    float* __restrict__ cst) {
  __shared__ float te[TDIM];
  int u = threadIdx.x;
  if (u < TDIM) te[u] = cosf(t[0] * tw[u] + tb[u]);
  __syncthreads();
  float cr = b_ih[u] + b_hh[u];
  float cz = b_ih[256 + u] + b_hh[256 + u];
  float ci = b_ih[512 + u];
  for (int k = 0; k < TDIM; ++k) {
    float tk = te[k];
    cr = fmaf(tk, W_ih[(size_t)u * 384 + 256 + k], cr);
    cz = fmaf(tk, W_ih[(size_t)(256 + u) * 384 + 256 + k], cz);
    ci = fmaf(tk, W_ih[(size_t)(512 + u) * 384 + 256 + k], ci);
  }
  cst[u] = cr;
  cst[256 + u] = cz;
  cst[512 + u] = ci;
  cst[768 + u] = b_hh[512 + u];
}

// ---------------- MFMA GEMM: C = A * B^T with hi/lo split operands ----------------
// Block 128x256, 4 waves (2x2), wave tile 64x128 (4 m-frags x 8 n-frags of 16x16x32).
// GCN epilogue: relu(acc+bias) -> split bf16 planes. GRU epilogue: fused gates -> fp32 out.
#define PK 40  // padded LDS row stride in bf16 units (80B)
template <bool GRU>
__global__ __launch_bounds__(256, 2) void gemm_mfma(const short* __restrict__ AH,
                                                    const short* __restrict__ AL,
                                                    const short* __restrict__ BHi,
                                                    const short* __restrict__ BLo,
                                                    const float* __restrict__ bias,
                                                    const float* __restrict__ cst,
                                                    const short* __restrict__ hHp,
                                                    const short* __restrict__ hLp,
                                                    short* __restrict__ outH,
                                                    short* __restrict__ outL,
                                                    float* __restrict__ outF) {
  __shared__ __align__(16) short As[2 * 128 * PK];
  __shared__ __align__(16) short Bs[2 * 256 * PK];
  const int tid = threadIdx.x;
  const int row0 = blockIdx.x * 128;
  const int col0 = blockIdx.y * 256;
  const int l = tid & 63, wv = tid >> 6;
  const int wm = wv >> 1, wn = wv & 1;
  const int fr = l & 15, fg = l >> 4;

  f32x4 acc[4][8];
#pragma unroll
  for (int i = 0; i < 4; ++i)
#pragma unroll
    for (int j = 0; j < 8; ++j) acc[i][j] = (f32x4)(0.0f);

  for (int k0 = 0; k0 < HID; k0 += 32) {
    // ---- stage A (128 rows x 32 k, 2 planes) ----
#pragma unroll
    for (int i = 0; i < 4; ++i) {
      int id = tid + i * 256;       // 0..1023
      int pl = id >> 9;
      int c = id & 511;
      int row = c >> 2, kc = c & 3;
      int gr = row0 + row;
      gr = gr < NN ? gr : NN - 1;
      const short* sp = pl ? AL : AH;
      uint4 v = *(const uint4*)(sp + (size_t)gr * HID + k0 + kc * 8);
      *(uint4*)(As + pl * 128 * PK + row * PK + kc * 8) = v;
    }
    // ---- stage B (256 rows x 32 k, 2 planes) ----
#pragma unroll
    for (int i = 0; i < 8; ++i) {
      int id = tid + i * 256;       // 0..2047
      int pl = id >> 10;
      int c = id & 1023;
      int row = c >> 2, kc = c & 3;
      const short* sp = pl ? BLo : BHi;
      uint4 v = *(const uint4*)(sp + (size_t)(col0 + row) * HID + k0 + kc * 8);
      *(uint4*)(Bs + pl * 256 * PK + row * PK + kc * 8) = v;
    }
    __syncthreads();

    bf16x8 bh[8], bl[8];
#pragma unroll
    for (int nf = 0; nf < 8; ++nf) {
      int r = wn * 128 + nf * 16 + fr;
      bh[nf] = *(const bf16x8*)(Bs + r * PK + fg * 8);
      bl[nf] = *(const bf16x8*)(Bs + 256 * PK + r * PK + fg * 8);
    }
#pragma unroll
    for (int mf = 0; mf < 4; ++mf) {
      int r = wm * 64 + mf * 16 + fr;
      bf16x8 ah = *(const bf16x8*)(As + r * PK + fg * 8);
      bf16x8 al = *(const bf16x8*)(As + 128 * PK + r * PK + fg * 8);
#pragma unroll
      for (int nf = 0; nf < 8; ++nf)
        acc[mf][nf] = __builtin_amdgcn_mfma_f32_16x16x32_bf16(ah, bh[nf], acc[mf][nf], 0, 0, 0);
#pragma unroll
      for (int nf = 0; nf < 8; ++nf)
        acc[mf][nf] = __builtin_amdgcn_mfma_f32_16x16x32_bf16(ah, bl[nf], acc[mf][nf], 0, 0, 0);
#pragma unroll
      for (int nf = 0; nf < 8; ++nf)
        acc[mf][nf] = __builtin_amdgcn_mfma_f32_16x16x32_bf16(al, bh[nf], acc[mf][nf], 0, 0, 0);
    }
    __syncthreads();
  }

  if constexpr (!GRU) {
#pragma unroll
    for (int mf = 0; mf < 4; ++mf) {
      int rbase = row0 + wm * 64 + mf * 16 + fg * 4;
#pragma unroll
      for (int nf = 0; nf < 8; ++nf) {
        int c = wn * 128 + nf * 16 + fr;   // col0 == 0 for GCN
        float bs = bias[c];
#pragma unroll
        for (int j = 0; j < 4; ++j) {
          int row = rbase + j;
          if (row < NN) {
            float v = fmaxf(acc[mf][nf][j] + bs, 0.0f);
            unsigned short hv_ = f2bf(v);
            float lo = v - bf2f(hv_);
            size_t off = (size_t)row * HID + c;
            outH[off] = (short)hv_;
            outL[off] = (short)f2bf(lo);
          }
        }
      }
    }
  } else {
#pragma unroll
    for (int mf = 0; mf < 4; ++mf) {
      int rbase = row0 + wm * 64 + mf * 16 + fg * 4;
#pragma unroll
      for (int ug = 0; ug < 2; ++ug) {
        int ub = ((col0 >> 6) + wn * 2 + ug) * 16 + fr;   // unit index
        float cr = cst[ub], cz = cst[256 + ub], ci = cst[512 + ub], chn = cst[768 + ub];
#pragma unroll
        for (int j = 0; j < 4; ++j) {
          int row = rbase + j;
          if (row < NN) {
            float dr = acc[mf][ug * 4 + 0][j] + cr;
            float dz = acc[mf][ug * 4 + 1][j] + cz;
            float dn = acc[mf][ug * 4 + 2][j] + ci;
            float dh = acc[mf][ug * 4 + 3][j] + chn;
            float rg = 1.0f / (1.0f + __expf(-dr));
            float zg = 1.0f / (1.0f + __expf(-dz));
            float ng = tanhf(dn + rg * dh);
            size_t off = (size_t)row * HID + ub;
            float hv = bf2f((unsigned short)hHp[off]) + bf2f((unsigned short)hLp[off]);
            outF[off] = (1.0f - zg) * ng + zg * hv;
          }
        }
      }
    }
  }
}

extern "C" void kernel_launch(void* const* d_in, const int* in_sizes, int n_in,
                              void* d_out, int out_size, void* d_ws, size_t ws_size,
                              hipStream_t stream) {
  const float* hidden = (const float*)d_in[0];
  const float* t      = (const float*)d_in[1];
  const int*   src    = (const int*)d_in[2];
  const int*   dst    = (const int*)d_in[3];
  const float* W1     = (const float*)d_in[4];
  const float* b1     = (const float*)d_in[5];
  const float* W2     = (const float*)d_in[6];
  const float* b2     = (const float*)d_in[7];
  const float* time_w = (const float*)d_in[8];
  const float* time_b = (const float*)d_in[9];
  const float* W_ih   = (const float*)d_in[10];
  const float* W_hh   = (const float*)d_in[11];
  const float* b_ih   = (const float*)d_in[12];
  const float* b_hh   = (const float*)d_in[13];
  float* out = (float*)d_out;

  char* p = (char*)d_ws;
  float* onorm = (float*)p;      p += 50048 * 4;
  float* inorm = (float*)p;      p += 50048 * 4;
  float* cst   = (float*)p;      p += 1024 * 4;
  int* rowstart = (int*)p;       p += 50052 * 4;
  int* cursor   = (int*)p;       p += 50048 * 4;
  int* ecol     = (int*)p;       p += 800000 * 4;
  const size_t NF = (size_t)NN * HID;
  short* aggH = (short*)p;       p += NF * 2;
  short* aggL = (short*)p;       p += NF * 2;
  short* hH   = (short*)p;       p += NF * 2;
  short* hL   = (short*)p;       p += NF * 2;
  short* W1H  = (short*)p;       p += 65536 * 2;
  short* W1L  = (short*)p;       p += 65536 * 2;
  short* W2H  = (short*)p;       p += 65536 * 2;
  short* W2L  = (short*)p;       p += 65536 * 2;
  short* WgH  = (short*)p;       p += 262144 * 2;
  short* WgL  = (short*)p;       p += 262144 * 2;

  // degrees -> CSR scan -> norms
  hipMemsetAsync(onorm, 0, 100096 * sizeof(float), stream);
  deg_kernel<<<NE / 256, 256, 0, stream>>>(src, dst, onorm, inorm);
  scan_rows<<<1, 1024, 0, stream>>>(inorm, rowstart, cursor);   // raw counts
  norm_kernel<<<(NN + 255) / 256, 256, 0, stream>>>(onorm, inorm);
  fill_csr<<<(NE + 255) / 256, 256, 0, stream>>>(src, dst, cursor, ecol);

  // weight prep
  transpose_split<<<256, 256, 0, stream>>>(W1, W2, W1H, W1L, W2H, W2L);
  build_wg<<<256, 256, 0, stream>>>(W_ih, W_hh, WgH, WgL);
  build_consts<<<1, 256, 0, stream>>>(t, time_w, time_b, W_ih, b_ih, b_hh, cst);

  const int gather_blocks = (NN + 3) / 4;
  dim3 gGcn((NN + 127) / 128, 1);
  dim3 gGru((NN + 127) / 128, 4);

  // layer 1
  gather_agg<false><<<gather_blocks, 256, 0, stream>>>(hidden, nullptr, nullptr, rowstart, ecol, onorm, inorm, aggH, aggL);
  gemm_mfma<false><<<gGcn, 256, 0, stream>>>(aggH, aggL, W1H, W1L, b1, nullptr, nullptr, nullptr, hH, hL, nullptr);

  // layer 2 (relu fused)
  gather_agg<true><<<gather_blocks, 256, 0, stream>>>(nullptr, hH, hL, rowstart, ecol, onorm, inorm, aggH, aggL);
  gemm_mfma<false><<<gGcn, 256, 0, stream>>>(aggH, aggL, W2H, W2L, b2, nullptr, nullptr, nullptr, hH, hL, nullptr);

  // GRU: fused gate GEMM -> out
  gemm_mfma<true><<<gGru, 256, 0, stream>>>(hH, hL, WgH, WgL, nullptr, cst, hH, hL, nullptr, nullptr, out);
}

// Round 4
// 708.542 us; speedup vs baseline: 2.7124x; 1.0306x over previous
//
#include <hip/hip_runtime.h>
#include <cstdint>
#include <cstddef>

#define NN 50000
#define NE 800000
#define HID 256
#define TDIM 128

typedef short bf16x8 __attribute__((ext_vector_type(8)));
typedef float f32x4 __attribute__((ext_vector_type(4)));

__device__ inline unsigned short f2bf(float f) {
  uint32_t u = __builtin_bit_cast(uint32_t, f);
  uint32_t r = u + 0x7FFFu + ((u >> 16) & 1u);
  return (unsigned short)(r >> 16);
}
__device__ inline float bf2f(unsigned short s) {
  uint32_t u = ((uint32_t)s) << 16;
  return __builtin_bit_cast(float, u);
}

// ---------------- degree / norm ----------------
__global__ __launch_bounds__(256) void deg_kernel(const int* __restrict__ src,
                                                  const int* __restrict__ dst,
                                                  float* __restrict__ od,
                                                  float* __restrict__ idg) {
  int i = blockIdx.x * 256 + threadIdx.x;
  if (i < NE) {
    atomicAdd(&od[src[i]], 1.0f);
    atomicAdd(&idg[dst[i]], 1.0f);
  }
}

__global__ __launch_bounds__(256) void norm_kernel(float* __restrict__ od,
                                                   float* __restrict__ idg) {
  int i = blockIdx.x * 256 + threadIdx.x;
  if (i < NN) {
    od[i]  = 1.0f / sqrtf(fmaxf(od[i], 1.0f));
    idg[i] = 1.0f / sqrtf(fmaxf(idg[i], 1.0f));
  }
}

// ---------------- CSR build ----------------
__global__ __launch_bounds__(1024) void scan_rows(const float* __restrict__ idg,
                                                  int* __restrict__ rowstart,
                                                  int* __restrict__ cursor) {
  __shared__ int wsum[16];
  __shared__ int carry_s;
  const int tid = threadIdx.x, lane = tid & 63, w = tid >> 6;
  if (tid == 0) { carry_s = 0; rowstart[0] = 0; }
  __syncthreads();
  for (int base = 0; base < NN; base += 1024) {
    int i = base + tid;
    int v = (i < NN) ? (int)idg[i] : 0;
    int inc = v;
#pragma unroll
    for (int off = 1; off < 64; off <<= 1) {
      int t = __shfl_up(inc, off, 64);
      if (lane >= off) inc += t;
    }
    if (lane == 63) wsum[w] = inc;
    __syncthreads();
    int woff = 0;
    for (int k = 0; k < w; ++k) woff += wsum[k];
    int carry = carry_s;
    int excl = carry + woff + inc - v;
    if (i < NN) { rowstart[i + 1] = excl + v; cursor[i] = excl; }
    __syncthreads();
    if (tid == 1023) carry_s = carry + woff + inc;
    __syncthreads();
  }
}

// also writes per-edge weight = onorm[src] (removes dependent load in gather)
__global__ __launch_bounds__(256) void fill_csr(const int* __restrict__ src,
                                                const int* __restrict__ dst,
                                                const float* __restrict__ onorm,
                                                int* __restrict__ cursor,
                                                int* __restrict__ col,
                                                float* __restrict__ ewt) {
  int e = blockIdx.x * 256 + threadIdx.x;
  if (e < NE) {
    int d = dst[e];
    int s = src[e];
    int pos = atomicAdd(&cursor[d], 1);
    col[pos] = s;
    ewt[pos] = onorm[s];
  }
}

// ---------------- gather aggregation -> split bf16 planes ----------------
template <bool BF>
__device__ inline float4 loadx(const float* __restrict__ xf,
                               const short* __restrict__ xH,
                               const short* __restrict__ xL, size_t off) {
  if constexpr (!BF) {
    return *(const float4*)(xf + off);
  } else {
    uint2 uh = *(const uint2*)(xH + off);
    uint2 ul = *(const uint2*)(xL + off);
    float4 r;
    r.x = bf2f((unsigned short)(uh.x & 0xFFFF)) + bf2f((unsigned short)(ul.x & 0xFFFF));
    r.y = bf2f((unsigned short)(uh.x >> 16))    + bf2f((unsigned short)(ul.x >> 16));
    r.z = bf2f((unsigned short)(uh.y & 0xFFFF)) + bf2f((unsigned short)(ul.y & 0xFFFF));
    r.w = bf2f((unsigned short)(uh.y >> 16))    + bf2f((unsigned short)(ul.y >> 16));
    return r;
  }
}

template <bool BF>
__global__ __launch_bounds__(256) void gather_agg(const float* __restrict__ xf,
                                                  const short* __restrict__ xH,
                                                  const short* __restrict__ xL,
                                                  const int* __restrict__ rowstart,
                                                  const int* __restrict__ col,
                                                  const float* __restrict__ ewt,
                                                  const float* __restrict__ inorm,
                                                  short* __restrict__ aggH,
                                                  short* __restrict__ aggL) {
  const int wid = blockIdx.x * 4 + (threadIdx.x >> 6);
  const int lane = threadIdx.x & 63;
  if (wid >= NN) return;
  const int e1 = rowstart[wid + 1];
  int e = rowstart[wid];
  const int fo = lane * 4;
  float a[4] = {0.f, 0.f, 0.f, 0.f};
  for (; e + 4 <= e1; e += 4) {
    int s0 = col[e], s1 = col[e + 1], s2 = col[e + 2], s3 = col[e + 3];
    float w0 = ewt[e], w1 = ewt[e + 1], w2 = ewt[e + 2], w3 = ewt[e + 3];
    float4 v0 = loadx<BF>(xf, xH, xL, (size_t)s0 * HID + fo);
    float4 v1 = loadx<BF>(xf, xH, xL, (size_t)s1 * HID + fo);
    float4 v2 = loadx<BF>(xf, xH, xL, (size_t)s2 * HID + fo);
    float4 v3 = loadx<BF>(xf, xH, xL, (size_t)s3 * HID + fo);
    a[0] = fmaf(v0.x, w0, a[0]); a[1] = fmaf(v0.y, w0, a[1]);
    a[2] = fmaf(v0.z, w0, a[2]); a[3] = fmaf(v0.w, w0, a[3]);
    a[0] = fmaf(v1.x, w1, a[0]); a[1] = fmaf(v1.y, w1, a[1]);
    a[2] = fmaf(v1.z, w1, a[2]); a[3] = fmaf(v1.w, w1, a[3]);
    a[0] = fmaf(v2.x, w2, a[0]); a[1] = fmaf(v2.y, w2, a[1]);
    a[2] = fmaf(v2.z, w2, a[2]); a[3] = fmaf(v2.w, w2, a[3]);
    a[0] = fmaf(v3.x, w3, a[0]); a[1] = fmaf(v3.y, w3, a[1]);
    a[2] = fmaf(v3.z, w3, a[2]); a[3] = fmaf(v3.w, w3, a[3]);
  }
  for (; e < e1; ++e) {
    int s0 = col[e];
    float w0 = ewt[e];
    float4 v0 = loadx<BF>(xf, xH, xL, (size_t)s0 * HID + fo);
    a[0] = fmaf(v0.x, w0, a[0]); a[1] = fmaf(v0.y, w0, a[1]);
    a[2] = fmaf(v0.z, w0, a[2]); a[3] = fmaf(v0.w, w0, a[3]);
  }
  const float wi = inorm[wid];
  float r[4];
  r[0] = a[0] * wi; r[1] = a[1] * wi; r[2] = a[2] * wi; r[3] = a[3] * wi;
  unsigned int hb[2], lb[2];
#pragma unroll
  for (int q = 0; q < 2; ++q) {
    unsigned short h0 = f2bf(r[q * 2 + 0]);
    unsigned short h1 = f2bf(r[q * 2 + 1]);
    unsigned short l0 = f2bf(r[q * 2 + 0] - bf2f(h0));
    unsigned short l1 = f2bf(r[q * 2 + 1] - bf2f(h1));
    hb[q] = (unsigned int)h0 | ((unsigned int)h1 << 16);
    lb[q] = (unsigned int)l0 | ((unsigned int)l1 << 16);
  }
  size_t off = (size_t)wid * HID + fo;
  *(uint2*)(aggH + off) = make_uint2(hb[0], hb[1]);
  *(uint2*)(aggL + off) = make_uint2(lb[0], lb[1]);
}

// ---------------- weight prep ----------------
__global__ __launch_bounds__(256) void transpose_split(const float* __restrict__ W1,
                                                       const float* __restrict__ W2,
                                                       short* __restrict__ W1H, short* __restrict__ W1L,
                                                       short* __restrict__ W2H, short* __restrict__ W2L) {
  int n = blockIdx.x, k = threadIdx.x;
  float a = W1[k * 256 + n];
  unsigned short h = f2bf(a);
  W1H[n * 256 + k] = (short)h;
  W1L[n * 256 + k] = (short)f2bf(a - bf2f(h));
  float b = W2[k * 256 + n];
  unsigned short h2 = f2bf(b);
  W2H[n * 256 + k] = (short)h2;
  W2L[n * 256 + k] = (short)f2bf(b - bf2f(h2));
}

// Wg row layout: gate-blocked by 16: row(u,g) = (u>>4)*64 + g*16 + (u&15). hi plane only.
__global__ __launch_bounds__(256) void build_wg(const float* __restrict__ W_ih,
                                                const float* __restrict__ W_hh,
                                                short* __restrict__ WgH) {
  int u = blockIdx.x, k = threadIdx.x;
  int base = (u >> 4) * 64 + (u & 15);
  float v[4];
  v[0] = W_ih[(size_t)u * 384 + k] + W_hh[(size_t)u * 256 + k];
  v[1] = W_ih[(size_t)(256 + u) * 384 + k] + W_hh[(size_t)(256 + u) * 256 + k];
  v[2] = W_ih[(size_t)(512 + u) * 384 + k];
  v[3] = W_hh[(size_t)(512 + u) * 256 + k];
#pragma unroll
  for (int g = 0; g < 4; ++g)
    WgH[(size_t)(base + g * 16) * 256 + k] = (short)f2bf(v[g]);
}

__global__ __launch_bounds__(256) void build_consts(const float* __restrict__ t,
                                                    const float* __restrict__ tw,
                                                    const float* __restrict__ tb,
                                                    const float* __restrict__ W_ih,
                                                    const float* __restrict__ b_ih,
                                                    const float* __restrict__ b_hh,
                                                    float* __restrict__ cst) {
  __shared__ float te[TDIM];
  int u = threadIdx.x;
  if (u < TDIM) te[u] = cosf(t[0] * tw[u] + tb[u]);
  __syncthreads();
  float cr = b_ih[u] + b_hh[u];
  float cz = b_ih[256 + u] + b_hh[256 + u];
  float ci = b_ih[512 + u];
  for (int k = 0; k < TDIM; ++k) {
    float tk = te[k];
    cr = fmaf(tk, W_ih[(size_t)u * 384 + 256 + k], cr);
    cz = fmaf(tk, W_ih[(size_t)(256 + u) * 384 + 256 + k], cz);
    ci = fmaf(tk, W_ih[(size_t)(512 + u) * 384 + 256 + k], ci);
  }
  cst[u] = cr;
  cst[256 + u] = cz;
  cst[512 + u] = ci;
  cst[768 + u] = b_hh[512 + u];
}

// ---------------- MFMA GEMM v2 ----------------
// Block 128 x BN (BN = NF*32), 4 waves (2x2), wave tile 64 x NF*16.
// TWOPL: 3-product hi/lo (GCN). else single bf16 product (GRU).
// LDS rows of 64B (32 k-shorts), slot-rotated swizzle: s' = (s + (row>>1)) & 3.
template <int NF, int CT, bool TWOPL, bool GRUE>
__global__ __launch_bounds__(256, 2) void gemm_v2(const short* __restrict__ AH,
                                                  const short* __restrict__ AL,
                                                  const short* __restrict__ BH,
                                                  const short* __restrict__ BL,
                                                  const float* __restrict__ bias,
                                                  const float* __restrict__ cst,
                                                  const short* __restrict__ hHp,
                                                  const short* __restrict__ hLp,
                                                  short* __restrict__ outH,
                                                  short* __restrict__ outL,
                                                  float* __restrict__ outF) {
  constexpr int BN = NF * 32;
  constexpr int APL = TWOPL ? 2 : 1;
  __shared__ __align__(16) short As[APL * 128 * 32];
  __shared__ __align__(16) short Bs[APL * BN * 32];

  const int bid = blockIdx.x;
  const int strip = bid / CT;
  const int ct = bid % CT;
  const int row0 = strip * 128;
  const int col0 = ct * BN;
  const int tid = threadIdx.x;
  const int l = tid & 63, wv = tid >> 6;
  const int wm = wv >> 1, wn = wv & 1;
  const int fr = l & 15, fg = l >> 4;

  f32x4 acc[4][NF];
#pragma unroll
  for (int i = 0; i < 4; ++i)
#pragma unroll
    for (int j = 0; j < NF; ++j) acc[i][j] = (f32x4)(0.0f);

  for (int k0 = 0; k0 < HID; k0 += 32) {
    // ---- stage A: 128 rows x 4 slots x APL planes ----
#pragma unroll
    for (int i = 0; i < (128 * 4 * APL) / 256; ++i) {
      int id = tid + i * 256;
      int pl = id >> 9;           // APL==1 -> always 0
      int c = id & 511;
      int row = c >> 2, slot = c & 3;
      int gr = row0 + row;
      gr = gr < NN ? gr : NN - 1;
      const short* sp = pl ? AL : AH;
      uint4 v = *(const uint4*)(sp + (size_t)gr * HID + k0 + slot * 8);
      int sl = (slot + (row >> 1)) & 3;
      *(uint4*)(As + pl * (128 * 32) + row * 32 + sl * 8) = v;
    }
    // ---- stage B: BN rows x 4 slots x APL planes ----
#pragma unroll
    for (int i = 0; i < (BN * 4 * APL) / 256; ++i) {
      int id = tid + i * 256;
      int pl = id / (BN * 4);
      int c = id % (BN * 4);
      int row = c >> 2, slot = c & 3;
      const short* sp = pl ? BL : BH;
      uint4 v = *(const uint4*)(sp + (size_t)(col0 + row) * HID + k0 + slot * 8);
      int sl = (slot + (row >> 1)) & 3;
      *(uint4*)(Bs + pl * (BN * 32) + row * 32 + sl * 8) = v;
    }
    __syncthreads();

    bf16x8 bh[NF], bl[NF];
#pragma unroll
    for (int nf = 0; nf < NF; ++nf) {
      int r = wn * (NF * 16) + nf * 16 + fr;
      int ra = r * 32 + (((fg + (r >> 1)) & 3) << 3);
      bh[nf] = *(const bf16x8*)(Bs + ra);
      if constexpr (TWOPL) bl[nf] = *(const bf16x8*)(Bs + BN * 32 + ra);
    }
#pragma unroll
    for (int mf = 0; mf < 4; ++mf) {
      int r = wm * 64 + mf * 16 + fr;
      int ra = r * 32 + (((fg + (r >> 1)) & 3) << 3);
      bf16x8 ah = *(const bf16x8*)(As + ra);
      if constexpr (TWOPL) {
        bf16x8 al = *(const bf16x8*)(As + 128 * 32 + ra);
#pragma unroll
        for (int nf = 0; nf < NF; ++nf)
          acc[mf][nf] = __builtin_amdgcn_mfma_f32_16x16x32_bf16(ah, bh[nf], acc[mf][nf], 0, 0, 0);
#pragma unroll
        for (int nf = 0; nf < NF; ++nf)
          acc[mf][nf] = __builtin_amdgcn_mfma_f32_16x16x32_bf16(ah, bl[nf], acc[mf][nf], 0, 0, 0);
#pragma unroll
        for (int nf = 0; nf < NF; ++nf)
          acc[mf][nf] = __builtin_amdgcn_mfma_f32_16x16x32_bf16(al, bh[nf], acc[mf][nf], 0, 0, 0);
      } else {
#pragma unroll
        for (int nf = 0; nf < NF; ++nf)
          acc[mf][nf] = __builtin_amdgcn_mfma_f32_16x16x32_bf16(ah, bh[nf], acc[mf][nf], 0, 0, 0);
      }
    }
    __syncthreads();
  }

  if constexpr (!GRUE) {
    // relu(acc + bias) -> split bf16 planes
#pragma unroll
    for (int mf = 0; mf < 4; ++mf) {
      int rbase = row0 + wm * 64 + mf * 16 + fg * 4;
#pragma unroll
      for (int nf = 0; nf < NF; ++nf) {
        int c = col0 + wn * (NF * 16) + nf * 16 + fr;
        float bs = bias[c];
#pragma unroll
        for (int j = 0; j < 4; ++j) {
          int row = rbase + j;
          if (row < NN) {
            float v = fmaxf(acc[mf][nf][j] + bs, 0.0f);
            unsigned short hv_ = f2bf(v);
            size_t off = (size_t)row * HID + c;
            outH[off] = (short)hv_;
            outL[off] = (short)f2bf(v - bf2f(hv_));
          }
        }
      }
    }
  } else {
    // fused GRU gates -> fp32 out
#pragma unroll
    for (int mf = 0; mf < 4; ++mf) {
      int rbase = row0 + wm * 64 + mf * 16 + fg * 4;
#pragma unroll
      for (int ug = 0; ug < 2; ++ug) {
        int group = ct * 4 + wn * 2 + ug;
        int u = group * 16 + fr;
        float cr = cst[u], cz = cst[256 + u], ci = cst[512 + u], chn = cst[768 + u];
#pragma unroll
        for (int j = 0; j < 4; ++j) {
          int row = rbase + j;
          if (row < NN) {
            float dr = acc[mf][ug * 4 + 0][j] + cr;
            float dz = acc[mf][ug * 4 + 1][j] + cz;
            float dn = acc[mf][ug * 4 + 2][j] + ci;
            float dh = acc[mf][ug * 4 + 3][j] + chn;
            float rg = 1.0f / (1.0f + __expf(-dr));
            float zg = 1.0f / (1.0f + __expf(-dz));
            float ng = tanhf(dn + rg * dh);
            size_t off = (size_t)row * HID + u;
            float hv = bf2f((unsigned short)hHp[off]) + bf2f((unsigned short)hLp[off]);
            outF[off] = (1.0f - zg) * ng + zg * hv;
          }
        }
      }
    }
  }
}

extern "C" void kernel_launch(void* const* d_in, const int* in_sizes, int n_in,
                              void* d_out, int out_size, void* d_ws, size_t ws_size,
                              hipStream_t stream) {
  const float* hidden = (const float*)d_in[0];
  const float* t      = (const float*)d_in[1];
  const int*   src    = (const int*)d_in[2];
  const int*   dst    = (const int*)d_in[3];
  const float* W1     = (const float*)d_in[4];
  const float* b1     = (const float*)d_in[5];
  const float* W2     = (const float*)d_in[6];
  const float* b2     = (const float*)d_in[7];
  const float* time_w = (const float*)d_in[8];
  const float* time_b = (const float*)d_in[9];
  const float* W_ih   = (const float*)d_in[10];
  const float* W_hh   = (const float*)d_in[11];
  const float* b_ih   = (const float*)d_in[12];
  const float* b_hh   = (const float*)d_in[13];
  float* out = (float*)d_out;

  char* p = (char*)d_ws;
  float* onorm = (float*)p;      p += 50048 * 4;
  float* inorm = (float*)p;      p += 50048 * 4;
  float* cst   = (float*)p;      p += 1024 * 4;
  int* rowstart = (int*)p;       p += 50052 * 4;
  int* cursor   = (int*)p;       p += 50048 * 4;
  int* ecol     = (int*)p;       p += 800000 * 4;
  float* ewt    = (float*)p;     p += 800000 * 4;
  const size_t NF_ = (size_t)NN * HID;
  short* aggH = (short*)p;       p += NF_ * 2;
  short* aggL = (short*)p;       p += NF_ * 2;
  short* hH   = (short*)p;       p += NF_ * 2;
  short* hL   = (short*)p;       p += NF_ * 2;
  short* W1H  = (short*)p;       p += 65536 * 2;
  short* W1L  = (short*)p;       p += 65536 * 2;
  short* W2H  = (short*)p;       p += 65536 * 2;
  short* W2L  = (short*)p;       p += 65536 * 2;
  short* WgH  = (short*)p;       p += 262144 * 2;

  // degrees -> CSR scan -> norms -> CSR fill (with edge weights)
  hipMemsetAsync(onorm, 0, 100096 * sizeof(float), stream);
  deg_kernel<<<NE / 256, 256, 0, stream>>>(src, dst, onorm, inorm);
  scan_rows<<<1, 1024, 0, stream>>>(inorm, rowstart, cursor);   // raw counts
  norm_kernel<<<(NN + 255) / 256, 256, 0, stream>>>(onorm, inorm);
  fill_csr<<<(NE + 255) / 256, 256, 0, stream>>>(src, dst, onorm, cursor, ecol, ewt);

  // weight prep
  transpose_split<<<256, 256, 0, stream>>>(W1, W2, W1H, W1L, W2H, W2L);
  build_wg<<<256, 256, 0, stream>>>(W_ih, W_hh, WgH);
  build_consts<<<1, 256, 0, stream>>>(t, time_w, time_b, W_ih, b_ih, b_hh, cst);

  const int gather_blocks = (NN + 3) / 4;
  const int strips = (NN + 127) / 128;   // 391

  // layer 1: gather + 3-product GEMM (128x128 tiles, col-tile-fastest 1D grid)
  gather_agg<false><<<gather_blocks, 256, 0, stream>>>(hidden, nullptr, nullptr, rowstart, ecol, ewt, inorm, aggH, aggL);
  gemm_v2<4, 2, true, false><<<strips * 2, 256, 0, stream>>>(aggH, aggL, W1H, W1L, b1, nullptr, nullptr, nullptr, hH, hL, nullptr);

  // layer 2
  gather_agg<true><<<gather_blocks, 256, 0, stream>>>(nullptr, hH, hL, rowstart, ecol, ewt, inorm, aggH, aggL);
  gemm_v2<4, 2, true, false><<<strips * 2, 256, 0, stream>>>(aggH, aggL, W2H, W2L, b2, nullptr, nullptr, nullptr, hH, hL, nullptr);

  // GRU: single-product bf16 GEMM (128x256 tiles) with fused gate epilogue -> out
  gemm_v2<8, 4, false, true><<<strips * 4, 256, 0, stream>>>(hH, nullptr, WgH, nullptr, nullptr, cst, hH, hL, nullptr, nullptr, out);
}

// Round 5
// 492.198 us; speedup vs baseline: 3.9046x; 1.4395x over previous
//
#include <hip/hip_runtime.h>
#include <cstdint>
#include <cstddef>

#define NN 50000
#define NE 800000
#define HID 256
#define TDIM 128

typedef short bf16x8 __attribute__((ext_vector_type(8)));
typedef float f32x4 __attribute__((ext_vector_type(4)));

__device__ inline unsigned short f2bf(float f) {
  uint32_t u = __builtin_bit_cast(uint32_t, f);
  uint32_t r = u + 0x7FFFu + ((u >> 16) & 1u);
  return (unsigned short)(r >> 16);
}
__device__ inline float bf2f(unsigned short s) {
  uint32_t u = ((uint32_t)s) << 16;
  return __builtin_bit_cast(float, u);
}

// ---------------- hidden -> bf16 plane ----------------
__global__ __launch_bounds__(256) void cvt_hidden(const float* __restrict__ x,
                                                  short* __restrict__ xb) {
  int i = blockIdx.x * 256 + threadIdx.x;   // one float4 per thread
  if (i < NN * HID / 4) {
    float4 v = ((const float4*)x)[i];
    unsigned int lo = (unsigned int)f2bf(v.x) | ((unsigned int)f2bf(v.y) << 16);
    unsigned int hi = (unsigned int)f2bf(v.z) | ((unsigned int)f2bf(v.w) << 16);
    ((uint2*)xb)[i] = make_uint2(lo, hi);
  }
}

// ---------------- degree / norm ----------------
__global__ __launch_bounds__(256) void deg_kernel(const int* __restrict__ src,
                                                  const int* __restrict__ dst,
                                                  float* __restrict__ od,
                                                  float* __restrict__ idg) {
  int i = blockIdx.x * 256 + threadIdx.x;
  if (i < NE) {
    atomicAdd(&od[src[i]], 1.0f);
    atomicAdd(&idg[dst[i]], 1.0f);
  }
}

__global__ __launch_bounds__(256) void norm_kernel(float* __restrict__ od,
                                                   float* __restrict__ idg) {
  int i = blockIdx.x * 256 + threadIdx.x;
  if (i < NN) {
    od[i]  = 1.0f / sqrtf(fmaxf(od[i], 1.0f));
    idg[i] = 1.0f / sqrtf(fmaxf(idg[i], 1.0f));
  }
}

// ---------------- CSR scan: 8 elems/thread, 1024 threads, 7 iterations ----------------
__global__ __launch_bounds__(1024) void scan_rows(const float* __restrict__ idg,
                                                  int* __restrict__ rowstart,
                                                  int* __restrict__ cursor) {
  __shared__ int wsum[16];
  __shared__ int carry_s;
  const int tid = threadIdx.x, lane = tid & 63, w = tid >> 6;
  if (tid == 0) { carry_s = 0; rowstart[0] = 0; }
  __syncthreads();
  for (int base = 0; base < NN; base += 8192) {
    int i0 = base + tid * 8;
    int c[8];
    int v = 0;
#pragma unroll
    for (int j = 0; j < 8; ++j) {
      int i = i0 + j;
      c[j] = (i < NN) ? (int)idg[i] : 0;
      v += c[j];
    }
    int inc = v;
#pragma unroll
    for (int off = 1; off < 64; off <<= 1) {
      int t = __shfl_up(inc, off, 64);
      if (lane >= off) inc += t;
    }
    if (lane == 63) wsum[w] = inc;
    __syncthreads();
    int woff = 0;
    for (int k = 0; k < w; ++k) woff += wsum[k];
    int carry = carry_s;
    int run = carry + woff + inc - v;
#pragma unroll
    for (int j = 0; j < 8; ++j) {
      int i = i0 + j;
      if (i < NN) { cursor[i] = run; rowstart[i + 1] = run + c[j]; }
      run += c[j];
    }
    __syncthreads();
    if (tid == 1023) carry_s = carry + woff + inc;
    __syncthreads();
  }
}

// fill CSR; also stores per-edge weight = onorm[src]
__global__ __launch_bounds__(256) void fill_csr(const int* __restrict__ src,
                                                const int* __restrict__ dst,
                                                const float* __restrict__ onorm,
                                                int* __restrict__ cursor,
                                                int* __restrict__ col,
                                                float* __restrict__ ewt) {
  int e = blockIdx.x * 256 + threadIdx.x;
  if (e < NE) {
    int d = dst[e];
    int s = src[e];
    int pos = atomicAdd(&cursor[d], 1);
    col[pos] = s;
    ewt[pos] = onorm[s];
  }
}

// ---------------- gather aggregation (bf16 in -> bf16 out) ----------------
__global__ __launch_bounds__(256) void gather_agg(const short* __restrict__ xB,
                                                  const int* __restrict__ rowstart,
                                                  const int* __restrict__ col,
                                                  const float* __restrict__ ewt,
                                                  const float* __restrict__ inorm,
                                                  short* __restrict__ aggB) {
  const int wid = blockIdx.x * 4 + (threadIdx.x >> 6);
  const int lane = threadIdx.x & 63;
  if (wid >= NN) return;
  const int e1 = rowstart[wid + 1];
  int e = rowstart[wid];
  const int fo = lane * 4;
  float a[4] = {0.f, 0.f, 0.f, 0.f};
  for (; e + 4 <= e1; e += 4) {
    int s0 = col[e], s1 = col[e + 1], s2 = col[e + 2], s3 = col[e + 3];
    float w0 = ewt[e], w1 = ewt[e + 1], w2 = ewt[e + 2], w3 = ewt[e + 3];
    uint2 u0 = *(const uint2*)(xB + (size_t)s0 * HID + fo);
    uint2 u1 = *(const uint2*)(xB + (size_t)s1 * HID + fo);
    uint2 u2 = *(const uint2*)(xB + (size_t)s2 * HID + fo);
    uint2 u3 = *(const uint2*)(xB + (size_t)s3 * HID + fo);
    a[0] = fmaf(bf2f((unsigned short)(u0.x & 0xFFFF)), w0, a[0]);
    a[1] = fmaf(bf2f((unsigned short)(u0.x >> 16)),    w0, a[1]);
    a[2] = fmaf(bf2f((unsigned short)(u0.y & 0xFFFF)), w0, a[2]);
    a[3] = fmaf(bf2f((unsigned short)(u0.y >> 16)),    w0, a[3]);
    a[0] = fmaf(bf2f((unsigned short)(u1.x & 0xFFFF)), w1, a[0]);
    a[1] = fmaf(bf2f((unsigned short)(u1.x >> 16)),    w1, a[1]);
    a[2] = fmaf(bf2f((unsigned short)(u1.y & 0xFFFF)), w1, a[2]);
    a[3] = fmaf(bf2f((unsigned short)(u1.y >> 16)),    w1, a[3]);
    a[0] = fmaf(bf2f((unsigned short)(u2.x & 0xFFFF)), w2, a[0]);
    a[1] = fmaf(bf2f((unsigned short)(u2.x >> 16)),    w2, a[1]);
    a[2] = fmaf(bf2f((unsigned short)(u2.y & 0xFFFF)), w2, a[2]);
    a[3] = fmaf(bf2f((unsigned short)(u2.y >> 16)),    w2, a[3]);
    a[0] = fmaf(bf2f((unsigned short)(u3.x & 0xFFFF)), w3, a[0]);
    a[1] = fmaf(bf2f((unsigned short)(u3.x >> 16)),    w3, a[1]);
    a[2] = fmaf(bf2f((unsigned short)(u3.y & 0xFFFF)), w3, a[2]);
    a[3] = fmaf(bf2f((unsigned short)(u3.y >> 16)),    w3, a[3]);
  }
  for (; e < e1; ++e) {
    int s0 = col[e];
    float w0 = ewt[e];
    uint2 u0 = *(const uint2*)(xB + (size_t)s0 * HID + fo);
    a[0] = fmaf(bf2f((unsigned short)(u0.x & 0xFFFF)), w0, a[0]);
    a[1] = fmaf(bf2f((unsigned short)(u0.x >> 16)),    w0, a[1]);
    a[2] = fmaf(bf2f((unsigned short)(u0.y & 0xFFFF)), w0, a[2]);
    a[3] = fmaf(bf2f((unsigned short)(u0.y >> 16)),    w0, a[3]);
  }
  const float wi = inorm[wid];
  unsigned int lo = (unsigned int)f2bf(a[0] * wi) | ((unsigned int)f2bf(a[1] * wi) << 16);
  unsigned int hi = (unsigned int)f2bf(a[2] * wi) | ((unsigned int)f2bf(a[3] * wi) << 16);
  *(uint2*)(aggB + (size_t)wid * HID + fo) = make_uint2(lo, hi);
}

// ---------------- fused weight prep ----------------
// blocks 0..255: W1/W2 transpose->bf16 (row n = blockIdx)
// blocks 256..511: Wg build (unit u = blockIdx-256), gate-blocked rows
// block 512: time-encode consts
__global__ __launch_bounds__(256) void wprep(const float* __restrict__ W1,
                                             const float* __restrict__ W2,
                                             const float* __restrict__ W_ih,
                                             const float* __restrict__ W_hh,
                                             const float* __restrict__ t,
                                             const float* __restrict__ tw,
                                             const float* __restrict__ tb,
                                             const float* __restrict__ b_ih,
                                             const float* __restrict__ b_hh,
                                             short* __restrict__ W1B,
                                             short* __restrict__ W2B,
                                             short* __restrict__ WgB,
                                             float* __restrict__ cst) {
  const int b = blockIdx.x;
  const int k = threadIdx.x;
  if (b < 256) {
    W1B[b * 256 + k] = (short)f2bf(W1[k * 256 + b]);
    W2B[b * 256 + k] = (short)f2bf(W2[k * 256 + b]);
  } else if (b < 512) {
    int u = b - 256;
    int base = (u >> 4) * 64 + (u & 15);
    float v0 = W_ih[(size_t)u * 384 + k] + W_hh[(size_t)u * 256 + k];
    float v1 = W_ih[(size_t)(256 + u) * 384 + k] + W_hh[(size_t)(256 + u) * 256 + k];
    float v2 = W_ih[(size_t)(512 + u) * 384 + k];
    float v3 = W_hh[(size_t)(512 + u) * 256 + k];
    WgB[(size_t)(base + 0)  * 256 + k] = (short)f2bf(v0);
    WgB[(size_t)(base + 16) * 256 + k] = (short)f2bf(v1);
    WgB[(size_t)(base + 32) * 256 + k] = (short)f2bf(v2);
    WgB[(size_t)(base + 48) * 256 + k] = (short)f2bf(v3);
  } else {
    __shared__ float te[TDIM];
    int u = k;
    if (u < TDIM) te[u] = cosf(t[0] * tw[u] + tb[u]);
    __syncthreads();
    float cr = b_ih[u] + b_hh[u];
    float cz = b_ih[256 + u] + b_hh[256 + u];
    float ci = b_ih[512 + u];
    for (int kk = 0; kk < TDIM; ++kk) {
      float tk = te[kk];
      cr = fmaf(tk, W_ih[(size_t)u * 384 + 256 + kk], cr);
      cz = fmaf(tk, W_ih[(size_t)(256 + u) * 384 + 256 + kk], cz);
      ci = fmaf(tk, W_ih[(size_t)(512 + u) * 384 + 256 + kk], ci);
    }
    cst[u] = cr;
    cst[256 + u] = cz;
    cst[512 + u] = ci;
    cst[768 + u] = b_hh[512 + u];
  }
}

// ---------------- MFMA GEMM v3: single bf16 product ----------------
// Block 128 x BN (BN = NF*32), 4 waves (2x2), wave tile 64 x NF*16.
// LDS rows 64B, slot-rotated swizzle: s' = (s + (row>>1)) & 3.
// GRUE: fused GRU gate epilogue -> fp32. Else relu(acc+bias) -> bf16 (DUAL: +lo plane).
template <int NF, int CT, bool GRUE, bool DUAL>
__global__ __launch_bounds__(256, 2) void gemm_v3(const short* __restrict__ A,
                                                  const short* __restrict__ B,
                                                  const float* __restrict__ bias,
                                                  const float* __restrict__ cst,
                                                  const short* __restrict__ hHp,
                                                  const short* __restrict__ hLp,
                                                  short* __restrict__ outH,
                                                  short* __restrict__ outL,
                                                  float* __restrict__ outF) {
  constexpr int BN = NF * 32;
  __shared__ __align__(16) short As[128 * 32];
  __shared__ __align__(16) short Bs[BN * 32];

  const int bid = blockIdx.x;
  const int strip = bid / CT;
  const int ct = bid % CT;
  const int row0 = strip * 128;
  const int col0 = ct * BN;
  const int tid = threadIdx.x;
  const int l = tid & 63, wv = tid >> 6;
  const int wm = wv >> 1, wn = wv & 1;
  const int fr = l & 15, fg = l >> 4;

  f32x4 acc[4][NF];
#pragma unroll
  for (int i = 0; i < 4; ++i)
#pragma unroll
    for (int j = 0; j < NF; ++j) acc[i][j] = (f32x4)(0.0f);

  for (int k0 = 0; k0 < HID; k0 += 32) {
#pragma unroll
    for (int i = 0; i < 2; ++i) {   // A: 128 rows x 4 slots = 512 items
      int id = tid + i * 256;
      int row = id >> 2, slot = id & 3;
      int gr = row0 + row;
      gr = gr < NN ? gr : NN - 1;
      uint4 v = *(const uint4*)(A + (size_t)gr * HID + k0 + slot * 8);
      int sl = (slot + (row >> 1)) & 3;
      *(uint4*)(As + row * 32 + sl * 8) = v;
    }
#pragma unroll
    for (int i = 0; i < BN / 64; ++i) {  // B: BN rows x 4 slots
      int id = tid + i * 256;
      int row = id >> 2, slot = id & 3;
      uint4 v = *(const uint4*)(B + (size_t)(col0 + row) * HID + k0 + slot * 8);
      int sl = (slot + (row >> 1)) & 3;
      *(uint4*)(Bs + row * 32 + sl * 8) = v;
    }
    __syncthreads();

    bf16x8 bh[NF];
#pragma unroll
    for (int nf = 0; nf < NF; ++nf) {
      int r = wn * (NF * 16) + nf * 16 + fr;
      bh[nf] = *(const bf16x8*)(Bs + r * 32 + (((fg + (r >> 1)) & 3) << 3));
    }
#pragma unroll
    for (int mf = 0; mf < 4; ++mf) {
      int r = wm * 64 + mf * 16 + fr;
      bf16x8 ah = *(const bf16x8*)(As + r * 32 + (((fg + (r >> 1)) & 3) << 3));
#pragma unroll
      for (int nf = 0; nf < NF; ++nf)
        acc[mf][nf] = __builtin_amdgcn_mfma_f32_16x16x32_bf16(ah, bh[nf], acc[mf][nf], 0, 0, 0);
    }
    __syncthreads();
  }

  if constexpr (!GRUE) {
#pragma unroll
    for (int mf = 0; mf < 4; ++mf) {
      int rbase = row0 + wm * 64 + mf * 16 + fg * 4;
#pragma unroll
      for (int nf = 0; nf < NF; ++nf) {
        int c = col0 + wn * (NF * 16) + nf * 16 + fr;
        float bs = bias[c];
#pragma unroll
        for (int j = 0; j < 4; ++j) {
          int row = rbase + j;
          if (row < NN) {
            float v = fmaxf(acc[mf][nf][j] + bs, 0.0f);
            unsigned short hv_ = f2bf(v);
            size_t off = (size_t)row * HID + c;
            outH[off] = (short)hv_;
            if constexpr (DUAL) outL[off] = (short)f2bf(v - bf2f(hv_));
          }
        }
      }
    }
  } else {
#pragma unroll
    for (int mf = 0; mf < 4; ++mf) {
      int rbase = row0 + wm * 64 + mf * 16 + fg * 4;
#pragma unroll
      for (int ug = 0; ug < 2; ++ug) {
        int group = ct * 4 + wn * 2 + ug;
        int u = group * 16 + fr;
        float cr = cst[u], cz = cst[256 + u], ci = cst[512 + u], chn = cst[768 + u];
#pragma unroll
        for (int j = 0; j < 4; ++j) {
          int row = rbase + j;
          if (row < NN) {
            float dr = acc[mf][ug * 4 + 0][j] + cr;
            float dz = acc[mf][ug * 4 + 1][j] + cz;
            float dn = acc[mf][ug * 4 + 2][j] + ci;
            float dh = acc[mf][ug * 4 + 3][j] + chn;
            float rg = 1.0f / (1.0f + __expf(-dr));
            float zg = 1.0f / (1.0f + __expf(-dz));
            float ng = tanhf(dn + rg * dh);
            size_t off = (size_t)row * HID + u;
            float hv = bf2f((unsigned short)hHp[off]) + bf2f((unsigned short)hLp[off]);
            outF[off] = (1.0f - zg) * ng + zg * hv;
          }
        }
      }
    }
  }
}

extern "C" void kernel_launch(void* const* d_in, const int* in_sizes, int n_in,
                              void* d_out, int out_size, void* d_ws, size_t ws_size,
                              hipStream_t stream) {
  const float* hidden = (const float*)d_in[0];
  const float* t      = (const float*)d_in[1];
  const int*   src    = (const int*)d_in[2];
  const int*   dst    = (const int*)d_in[3];
  const float* W1     = (const float*)d_in[4];
  const float* b1     = (const float*)d_in[5];
  const float* W2     = (const float*)d_in[6];
  const float* b2     = (const float*)d_in[7];
  const float* time_w = (const float*)d_in[8];
  const float* time_b = (const float*)d_in[9];
  const float* W_ih   = (const float*)d_in[10];
  const float* W_hh   = (const float*)d_in[11];
  const float* b_ih   = (const float*)d_in[12];
  const float* b_hh   = (const float*)d_in[13];
  float* out = (float*)d_out;

  char* p = (char*)d_ws;
  float* onorm = (float*)p;      p += 50048 * 4;
  float* inorm = (float*)p;      p += 50048 * 4;
  float* cst   = (float*)p;      p += 1024 * 4;
  int* rowstart = (int*)p;       p += 50052 * 4;
  int* cursor   = (int*)p;       p += 50048 * 4;
  int* ecol     = (int*)p;       p += 800000 * 4;
  float* ewt    = (float*)p;     p += 800000 * 4;
  const size_t NFE = (size_t)NN * HID;
  short* Xb   = (short*)p;       p += NFE * 2;
  short* aggB = (short*)p;       p += NFE * 2;
  short* h1B  = (short*)p;       p += NFE * 2;
  short* h2H  = (short*)p;       p += NFE * 2;
  short* h2L  = (short*)p;       p += NFE * 2;
  short* W1B  = (short*)p;       p += 65536 * 2;
  short* W2B  = (short*)p;       p += 65536 * 2;
  short* WgB  = (short*)p;       p += 262144 * 2;

  // degrees -> CSR scan -> norms -> CSR fill
  hipMemsetAsync(onorm, 0, 100096 * sizeof(float), stream);
  cvt_hidden<<<(NN * HID / 4 + 255) / 256, 256, 0, stream>>>(hidden, Xb);
  deg_kernel<<<NE / 256, 256, 0, stream>>>(src, dst, onorm, inorm);
  scan_rows<<<1, 1024, 0, stream>>>(inorm, rowstart, cursor);   // raw counts
  norm_kernel<<<(NN + 255) / 256, 256, 0, stream>>>(onorm, inorm);
  fill_csr<<<(NE + 255) / 256, 256, 0, stream>>>(src, dst, onorm, cursor, ecol, ewt);

  // fused weight prep
  wprep<<<513, 256, 0, stream>>>(W1, W2, W_ih, W_hh, t, time_w, time_b, b_ih, b_hh,
                                 W1B, W2B, WgB, cst);

  const int gather_blocks = (NN + 3) / 4;
  const int strips = (NN + 127) / 128;   // 391

  // layer 1
  gather_agg<<<gather_blocks, 256, 0, stream>>>(Xb, rowstart, ecol, ewt, inorm, aggB);
  gemm_v3<4, 2, false, false><<<strips * 2, 256, 0, stream>>>(aggB, W1B, b1, nullptr, nullptr, nullptr, h1B, nullptr, nullptr);

  // layer 2 (writes hi+lo planes; lo only needed for GRU carry)
  gather_agg<<<gather_blocks, 256, 0, stream>>>(h1B, rowstart, ecol, ewt, inorm, aggB);
  gemm_v3<4, 2, false, true><<<strips * 2, 256, 0, stream>>>(aggB, W2B, b2, nullptr, nullptr, nullptr, h2H, h2L, nullptr);

  // GRU: single-product GEMM with fused gate epilogue -> out
  gemm_v3<8, 4, true, false><<<strips * 4, 256, 0, stream>>>(h2H, WgB, nullptr, cst, h2H, h2L, nullptr, nullptr, out);
}

// Round 6
// 442.036 us; speedup vs baseline: 4.3477x; 1.1135x over previous
//
#include <hip/hip_runtime.h>
#include <cstdint>
#include <cstddef>

#define NN 50000
#define NE 800000
#define HID 256
#define TDIM 128

typedef short bf16x8 __attribute__((ext_vector_type(8)));
typedef float f32x4 __attribute__((ext_vector_type(4)));

#define GLOAD_LDS16(g, l)                                                        \
  __builtin_amdgcn_global_load_lds(                                              \
      (const __attribute__((address_space(1))) unsigned int*)(g),                \
      (__attribute__((address_space(3))) unsigned int*)(l), 16, 0, 0)

__device__ inline unsigned short f2bf(float f) {
  uint32_t u = __builtin_bit_cast(uint32_t, f);
  uint32_t r = u + 0x7FFFu + ((u >> 16) & 1u);
  return (unsigned short)(r >> 16);
}
__device__ inline float bf2f(unsigned short s) {
  uint32_t u = ((uint32_t)s) << 16;
  return __builtin_bit_cast(float, u);
}

// ---------------- hidden -> bf16 plane ----------------
__global__ __launch_bounds__(256) void cvt_hidden(const float* __restrict__ x,
                                                  short* __restrict__ xb) {
  int i = blockIdx.x * 256 + threadIdx.x;   // one float4 per thread
  if (i < NN * HID / 4) {
    float4 v = ((const float4*)x)[i];
    unsigned int lo = (unsigned int)f2bf(v.x) | ((unsigned int)f2bf(v.y) << 16);
    unsigned int hi = (unsigned int)f2bf(v.z) | ((unsigned int)f2bf(v.w) << 16);
    ((uint2*)xb)[i] = make_uint2(lo, hi);
  }
}

// ---------------- degree / norm ----------------
__global__ __launch_bounds__(256) void deg_kernel(const int* __restrict__ src,
                                                  const int* __restrict__ dst,
                                                  float* __restrict__ od,
                                                  float* __restrict__ idg) {
  int i = blockIdx.x * 256 + threadIdx.x;
  if (i < NE) {
    atomicAdd(&od[src[i]], 1.0f);
    atomicAdd(&idg[dst[i]], 1.0f);
  }
}

__global__ __launch_bounds__(256) void norm_kernel(float* __restrict__ od,
                                                   float* __restrict__ idg) {
  int i = blockIdx.x * 256 + threadIdx.x;
  if (i < NN) {
    od[i]  = 1.0f / sqrtf(fmaxf(od[i], 1.0f));
    idg[i] = 1.0f / sqrtf(fmaxf(idg[i], 1.0f));
  }
}

// ---------------- CSR scan: 8 elems/thread ----------------
__global__ __launch_bounds__(1024) void scan_rows(const float* __restrict__ idg,
                                                  int* __restrict__ rowstart,
                                                  int* __restrict__ cursor) {
  __shared__ int wsum[16];
  __shared__ int carry_s;
  const int tid = threadIdx.x, lane = tid & 63, w = tid >> 6;
  if (tid == 0) { carry_s = 0; rowstart[0] = 0; }
  __syncthreads();
  for (int base = 0; base < NN; base += 8192) {
    int i0 = base + tid * 8;
    int c[8];
    int v = 0;
#pragma unroll
    for (int j = 0; j < 8; ++j) {
      int i = i0 + j;
      c[j] = (i < NN) ? (int)idg[i] : 0;
      v += c[j];
    }
    int inc = v;
#pragma unroll
    for (int off = 1; off < 64; off <<= 1) {
      int t = __shfl_up(inc, off, 64);
      if (lane >= off) inc += t;
    }
    if (lane == 63) wsum[w] = inc;
    __syncthreads();
    int woff = 0;
    for (int k = 0; k < w; ++k) woff += wsum[k];
    int carry = carry_s;
    int run = carry + woff + inc - v;
#pragma unroll
    for (int j = 0; j < 8; ++j) {
      int i = i0 + j;
      if (i < NN) { cursor[i] = run; rowstart[i + 1] = run + c[j]; }
      run += c[j];
    }
    __syncthreads();
    if (tid == 1023) carry_s = carry + woff + inc;
    __syncthreads();
  }
}

// fill CSR; also stores per-edge weight = onorm[src]
__global__ __launch_bounds__(256) void fill_csr(const int* __restrict__ src,
                                                const int* __restrict__ dst,
                                                const float* __restrict__ onorm,
                                                int* __restrict__ cursor,
                                                int* __restrict__ col,
                                                float* __restrict__ ewt) {
  int e = blockIdx.x * 256 + threadIdx.x;
  if (e < NE) {
    int d = dst[e];
    int s = src[e];
    int pos = atomicAdd(&cursor[d], 1);
    col[pos] = s;
    ewt[pos] = onorm[s];
  }
}

// ---------------- gather aggregation (bf16 in -> bf16 out) ----------------
__global__ __launch_bounds__(256) void gather_agg(const short* __restrict__ xB,
                                                  const int* __restrict__ rowstart,
                                                  const int* __restrict__ col,
                                                  const float* __restrict__ ewt,
                                                  const float* __restrict__ inorm,
                                                  short* __restrict__ aggB) {
  const int wid = blockIdx.x * 4 + (threadIdx.x >> 6);
  const int lane = threadIdx.x & 63;
  if (wid >= NN) return;
  const int e1 = rowstart[wid + 1];
  int e = rowstart[wid];
  const int fo = lane * 4;
  float a[4] = {0.f, 0.f, 0.f, 0.f};
  for (; e + 4 <= e1; e += 4) {
    int s0 = col[e], s1 = col[e + 1], s2 = col[e + 2], s3 = col[e + 3];
    float w0 = ewt[e], w1 = ewt[e + 1], w2 = ewt[e + 2], w3 = ewt[e + 3];
    uint2 u0 = *(const uint2*)(xB + (size_t)s0 * HID + fo);
    uint2 u1 = *(const uint2*)(xB + (size_t)s1 * HID + fo);
    uint2 u2 = *(const uint2*)(xB + (size_t)s2 * HID + fo);
    uint2 u3 = *(const uint2*)(xB + (size_t)s3 * HID + fo);
    a[0] = fmaf(bf2f((unsigned short)(u0.x & 0xFFFF)), w0, a[0]);
    a[1] = fmaf(bf2f((unsigned short)(u0.x >> 16)),    w0, a[1]);
    a[2] = fmaf(bf2f((unsigned short)(u0.y & 0xFFFF)), w0, a[2]);
    a[3] = fmaf(bf2f((unsigned short)(u0.y >> 16)),    w0, a[3]);
    a[0] = fmaf(bf2f((unsigned short)(u1.x & 0xFFFF)), w1, a[0]);
    a[1] = fmaf(bf2f((unsigned short)(u1.x >> 16)),    w1, a[1]);
    a[2] = fmaf(bf2f((unsigned short)(u1.y & 0xFFFF)), w1, a[2]);
    a[3] = fmaf(bf2f((unsigned short)(u1.y >> 16)),    w1, a[3]);
    a[0] = fmaf(bf2f((unsigned short)(u2.x & 0xFFFF)), w2, a[0]);
    a[1] = fmaf(bf2f((unsigned short)(u2.x >> 16)),    w2, a[1]);
    a[2] = fmaf(bf2f((unsigned short)(u2.y & 0xFFFF)), w2, a[2]);
    a[3] = fmaf(bf2f((unsigned short)(u2.y >> 16)),    w2, a[3]);
    a[0] = fmaf(bf2f((unsigned short)(u3.x & 0xFFFF)), w3, a[0]);
    a[1] = fmaf(bf2f((unsigned short)(u3.x >> 16)),    w3, a[1]);
    a[2] = fmaf(bf2f((unsigned short)(u3.y & 0xFFFF)), w3, a[2]);
    a[3] = fmaf(bf2f((unsigned short)(u3.y >> 16)),    w3, a[3]);
  }
  for (; e < e1; ++e) {
    int s0 = col[e];
    float w0 = ewt[e];
    uint2 u0 = *(const uint2*)(xB + (size_t)s0 * HID + fo);
    a[0] = fmaf(bf2f((unsigned short)(u0.x & 0xFFFF)), w0, a[0]);
    a[1] = fmaf(bf2f((unsigned short)(u0.x >> 16)),    w0, a[1]);
    a[2] = fmaf(bf2f((unsigned short)(u0.y & 0xFFFF)), w0, a[2]);
    a[3] = fmaf(bf2f((unsigned short)(u0.y >> 16)),    w0, a[3]);
  }
  const float wi = inorm[wid];
  unsigned int lo = (unsigned int)f2bf(a[0] * wi) | ((unsigned int)f2bf(a[1] * wi) << 16);
  unsigned int hi = (unsigned int)f2bf(a[2] * wi) | ((unsigned int)f2bf(a[3] * wi) << 16);
  *(uint2*)(aggB + (size_t)wid * HID + fo) = make_uint2(lo, hi);
}

// ---------------- fused weight prep ----------------
__global__ __launch_bounds__(256) void wprep(const float* __restrict__ W1,
                                             const float* __restrict__ W2,
                                             const float* __restrict__ W_ih,
                                             const float* __restrict__ W_hh,
                                             const float* __restrict__ t,
                                             const float* __restrict__ tw,
                                             const float* __restrict__ tb,
                                             const float* __restrict__ b_ih,
                                             const float* __restrict__ b_hh,
                                             short* __restrict__ W1B,
                                             short* __restrict__ W2B,
                                             short* __restrict__ WgB,
                                             float* __restrict__ cst) {
  const int b = blockIdx.x;
  const int k = threadIdx.x;
  if (b < 256) {
    W1B[b * 256 + k] = (short)f2bf(W1[k * 256 + b]);
    W2B[b * 256 + k] = (short)f2bf(W2[k * 256 + b]);
  } else if (b < 512) {
    int u = b - 256;
    int base = (u >> 4) * 64 + (u & 15);
    float v0 = W_ih[(size_t)u * 384 + k] + W_hh[(size_t)u * 256 + k];
    float v1 = W_ih[(size_t)(256 + u) * 384 + k] + W_hh[(size_t)(256 + u) * 256 + k];
    float v2 = W_ih[(size_t)(512 + u) * 384 + k];
    float v3 = W_hh[(size_t)(512 + u) * 256 + k];
    WgB[(size_t)(base + 0)  * 256 + k] = (short)f2bf(v0);
    WgB[(size_t)(base + 16) * 256 + k] = (short)f2bf(v1);
    WgB[(size_t)(base + 32) * 256 + k] = (short)f2bf(v2);
    WgB[(size_t)(base + 48) * 256 + k] = (short)f2bf(v3);
  } else {
    __shared__ float te[TDIM];
    int u = k;
    if (u < TDIM) te[u] = cosf(t[0] * tw[u] + tb[u]);
    __syncthreads();
    float cr = b_ih[u] + b_hh[u];
    float cz = b_ih[256 + u] + b_hh[256 + u];
    float ci = b_ih[512 + u];
    for (int kk = 0; kk < TDIM; ++kk) {
      float tk = te[kk];
      cr = fmaf(tk, W_ih[(size_t)u * 384 + 256 + kk], cr);
      cz = fmaf(tk, W_ih[(size_t)(256 + u) * 384 + 256 + kk], cz);
      ci = fmaf(tk, W_ih[(size_t)(512 + u) * 384 + 256 + kk], ci);
    }
    cst[u] = cr;
    cst[256 + u] = cz;
    cst[512 + u] = ci;
    cst[768 + u] = b_hh[512 + u];
  }
}

// ---------------- MFMA GEMM v4: global_load_lds staging, XCD-chunked blocks ----------------
// Block tile 128 x 128, 4 waves (2x2), wave tile 64x64 (4 m-frags x 4 n-frags of 16x16x32).
// LDS linear rows of 64B; slot-rotate swizzle realized by PRE-SWIZZLING the global source
// (global_load_lds dest must be linear: base + lane*16B). Read side uses s'=(fg+(r>>1))&3.
// GRUE: fused GRU gate epilogue -> fp32 out. Else relu(acc+bias) -> bf16 (+lo plane if DUAL).
template <int CT, bool GRUE, bool DUAL>
__global__ __launch_bounds__(256, 3) void gemm_v4(const short* __restrict__ A,
                                                  const short* __restrict__ B,
                                                  const float* __restrict__ bias,
                                                  const float* __restrict__ cst,
                                                  const short* __restrict__ hHp,
                                                  const short* __restrict__ hLp,
                                                  short* __restrict__ outH,
                                                  short* __restrict__ outL,
                                                  float* __restrict__ outF) {
  __shared__ __align__(16) short As[128 * 32];
  __shared__ __align__(16) short Bs[128 * 32];

  // bijective XCD-chunk swizzle (m204): all CT col-tiles of a strip -> same XCD L2
  const int nwg = gridDim.x;
  const int xcd = blockIdx.x & 7, jj = blockIdx.x >> 3;
  const int q = nwg >> 3, r = nwg & 7;
  const int lidx = (xcd < r ? xcd * (q + 1) : r * (q + 1) + (xcd - r) * q) + jj;
  const int strip = lidx / CT;
  const int ct = lidx % CT;
  const int row0 = strip * 128;
  const int col0 = ct * 128;

  const int tid = threadIdx.x;
  const int l = tid & 63, wv = tid >> 6;
  const int wm = wv >> 1, wn = wv & 1;
  const int fr = l & 15, fg = l >> 4;

  f32x4 acc[4][4];
#pragma unroll
  for (int i = 0; i < 4; ++i)
#pragma unroll
    for (int j = 0; j < 4; ++j) acc[i][j] = (f32x4)(0.0f);

  for (int k0 = 0; k0 < HID; k0 += 32) {
    // stage A: 128 rows x 4 slots, 16B each, direct-to-LDS (linear dest, pre-swz src)
#pragma unroll
    for (int i = 0; i < 2; ++i) {
      int id = tid + i * 256;
      int row = id >> 2, sp = id & 3;
      int s = (sp - (row >> 1)) & 3;
      int gr = row0 + row;
      gr = gr < NN ? gr : NN - 1;
      GLOAD_LDS16(A + (size_t)gr * HID + k0 + s * 8, As + id * 8);
    }
    // stage B
#pragma unroll
    for (int i = 0; i < 2; ++i) {
      int id = tid + i * 256;
      int row = id >> 2, sp = id & 3;
      int s = (sp - (row >> 1)) & 3;
      GLOAD_LDS16(B + (size_t)(col0 + row) * HID + k0 + s * 8, Bs + id * 8);
    }
    __syncthreads();

    bf16x8 bh[4];
#pragma unroll
    for (int nf = 0; nf < 4; ++nf) {
      int rr = wn * 64 + nf * 16 + fr;
      bh[nf] = *(const bf16x8*)(Bs + rr * 32 + (((fg + (rr >> 1)) & 3) << 3));
    }
#pragma unroll
    for (int mf = 0; mf < 4; ++mf) {
      int rr = wm * 64 + mf * 16 + fr;
      bf16x8 ah = *(const bf16x8*)(As + rr * 32 + (((fg + (rr >> 1)) & 3) << 3));
#pragma unroll
      for (int nf = 0; nf < 4; ++nf)
        acc[mf][nf] = __builtin_amdgcn_mfma_f32_16x16x32_bf16(ah, bh[nf], acc[mf][nf], 0, 0, 0);
    }
    __syncthreads();
  }

  if constexpr (!GRUE) {
#pragma unroll
    for (int mf = 0; mf < 4; ++mf) {
      int rbase = row0 + wm * 64 + mf * 16 + fg * 4;
#pragma unroll
      for (int nf = 0; nf < 4; ++nf) {
        int c = col0 + wn * 64 + nf * 16 + fr;
        float bs = bias[c];
#pragma unroll
        for (int j = 0; j < 4; ++j) {
          int row = rbase + j;
          if (row < NN) {
            float v = fmaxf(acc[mf][nf][j] + bs, 0.0f);
            unsigned short hv_ = f2bf(v);
            size_t off = (size_t)row * HID + c;
            outH[off] = (short)hv_;
            if constexpr (DUAL) outL[off] = (short)f2bf(v - bf2f(hv_));
          }
        }
      }
    }
  } else {
    // wave col window = 64 = one full gate-block of 16 units x 4 gates
    const int u = (ct * 2 + wn) * 16 + fr;
    const float cr = cst[u], cz = cst[256 + u], ci = cst[512 + u], chn = cst[768 + u];
#pragma unroll
    for (int mf = 0; mf < 4; ++mf) {
      int rbase = row0 + wm * 64 + mf * 16 + fg * 4;
#pragma unroll
      for (int j = 0; j < 4; ++j) {
        int row = rbase + j;
        if (row < NN) {
          float dr = acc[mf][0][j] + cr;
          float dz = acc[mf][1][j] + cz;
          float dn = acc[mf][2][j] + ci;
          float dh = acc[mf][3][j] + chn;
          float rg = 1.0f / (1.0f + __expf(-dr));
          float zg = 1.0f / (1.0f + __expf(-dz));
          float ng = tanhf(dn + rg * dh);
          size_t off = (size_t)row * HID + u;
          float hv = bf2f((unsigned short)hHp[off]) + bf2f((unsigned short)hLp[off]);
          outF[off] = (1.0f - zg) * ng + zg * hv;
        }
      }
    }
  }
}

extern "C" void kernel_launch(void* const* d_in, const int* in_sizes, int n_in,
                              void* d_out, int out_size, void* d_ws, size_t ws_size,
                              hipStream_t stream) {
  const float* hidden = (const float*)d_in[0];
  const float* t      = (const float*)d_in[1];
  const int*   src    = (const int*)d_in[2];
  const int*   dst    = (const int*)d_in[3];
  const float* W1     = (const float*)d_in[4];
  const float* b1     = (const float*)d_in[5];
  const float* W2     = (const float*)d_in[6];
  const float* b2     = (const float*)d_in[7];
  const float* time_w = (const float*)d_in[8];
  const float* time_b = (const float*)d_in[9];
  const float* W_ih   = (const float*)d_in[10];
  const float* W_hh   = (const float*)d_in[11];
  const float* b_ih   = (const float*)d_in[12];
  const float* b_hh   = (const float*)d_in[13];
  float* out = (float*)d_out;

  char* p = (char*)d_ws;
  float* onorm = (float*)p;      p += 50048 * 4;
  float* inorm = (float*)p;      p += 50048 * 4;
  float* cst   = (float*)p;      p += 1024 * 4;
  int* rowstart = (int*)p;       p += 50052 * 4;
  int* cursor   = (int*)p;       p += 50048 * 4;
  int* ecol     = (int*)p;       p += 800000 * 4;
  float* ewt    = (float*)p;     p += 800000 * 4;
  const size_t NFE = (size_t)NN * HID;
  short* Xb   = (short*)p;       p += NFE * 2;
  short* aggB = (short*)p;       p += NFE * 2;
  short* h1B  = (short*)p;       p += NFE * 2;
  short* h2H  = (short*)p;       p += NFE * 2;
  short* h2L  = (short*)p;       p += NFE * 2;
  short* W1B  = (short*)p;       p += 65536 * 2;
  short* W2B  = (short*)p;       p += 65536 * 2;
  short* WgB  = (short*)p;       p += 262144 * 2;

  // degrees -> CSR scan -> norms -> CSR fill
  hipMemsetAsync(onorm, 0, 100096 * sizeof(float), stream);
  cvt_hidden<<<(NN * HID / 4 + 255) / 256, 256, 0, stream>>>(hidden, Xb);
  deg_kernel<<<NE / 256, 256, 0, stream>>>(src, dst, onorm, inorm);
  scan_rows<<<1, 1024, 0, stream>>>(inorm, rowstart, cursor);   // raw counts
  norm_kernel<<<(NN + 255) / 256, 256, 0, stream>>>(onorm, inorm);
  fill_csr<<<(NE + 255) / 256, 256, 0, stream>>>(src, dst, onorm, cursor, ecol, ewt);

  // fused weight prep
  wprep<<<513, 256, 0, stream>>>(W1, W2, W_ih, W_hh, t, time_w, time_b, b_ih, b_hh,
                                 W1B, W2B, WgB, cst);

  const int gather_blocks = (NN + 3) / 4;
  const int strips = (NN + 127) / 128;   // 391

  // layer 1
  gather_agg<<<gather_blocks, 256, 0, stream>>>(Xb, rowstart, ecol, ewt, inorm, aggB);
  gemm_v4<2, false, false><<<strips * 2, 256, 0, stream>>>(aggB, W1B, b1, nullptr, nullptr, nullptr, h1B, nullptr, nullptr);

  // layer 2 (writes hi+lo planes; lo only needed for GRU carry)
  gather_agg<<<gather_blocks, 256, 0, stream>>>(h1B, rowstart, ecol, ewt, inorm, aggB);
  gemm_v4<2, false, true><<<strips * 2, 256, 0, stream>>>(aggB, W2B, b2, nullptr, nullptr, nullptr, h2H, h2L, nullptr);

  // GRU: 8 col-tiles per strip, XCD-chunked so A strip stays in one L2
  gemm_v4<8, true, false><<<strips * 8, 256, 0, stream>>>(h2H, WgB, nullptr, cst, h2H, h2L, nullptr, nullptr, out);
}

// Round 7
// 386.595 us; speedup vs baseline: 4.9712x; 1.1434x over previous
//
#include <hip/hip_runtime.h>
#include <cstdint>
#include <cstddef>

#define NN 50000
#define NE 800000
#define HID 256
#define TDIM 128

#define CHB 16384          // bins per histogram chunk (64 KB LDS)
#define NSL 16             // edge slices
#define SLE (NE / NSL)     // 50000 edges per slice

typedef short bf16x8 __attribute__((ext_vector_type(8)));
typedef float f32x4 __attribute__((ext_vector_type(4)));

#define GLOAD_LDS16(g, l)                                                        \
  __builtin_amdgcn_global_load_lds(                                              \
      (const __attribute__((address_space(1))) unsigned int*)(g),                \
      (__attribute__((address_space(3))) unsigned int*)(l), 16, 0, 0)

__device__ inline unsigned short f2bf(float f) {
  uint32_t u = __builtin_bit_cast(uint32_t, f);
  uint32_t r = u + 0x7FFFu + ((u >> 16) & 1u);
  return (unsigned short)(r >> 16);
}
__device__ inline float bf2f(unsigned short s) {
  uint32_t u = ((uint32_t)s) << 16;
  return __builtin_bit_cast(float, u);
}

// ---------------- hidden -> bf16 plane ----------------
__global__ __launch_bounds__(256) void cvt_hidden(const float* __restrict__ x,
                                                  short* __restrict__ xb) {
  int i = blockIdx.x * 256 + threadIdx.x;   // one float4 per thread
  if (i < NN * HID / 4) {
    float4 v = ((const float4*)x)[i];
    unsigned int lo = (unsigned int)f2bf(v.x) | ((unsigned int)f2bf(v.y) << 16);
    unsigned int hi = (unsigned int)f2bf(v.z) | ((unsigned int)f2bf(v.w) << 16);
    ((uint2*)xb)[i] = make_uint2(lo, hi);
  }
}

// ---------------- histogram phase A: LDS-privatized partial counts ----------------
// chunks 0..3: out-degree (src), 4..7: in-degree (dst). P[c][s][j], j in [0,CHB).
__global__ __launch_bounds__(1024) void hist_part(const int* __restrict__ src,
                                                  const int* __restrict__ dst,
                                                  int* __restrict__ P) {
  __shared__ int h[CHB];
  const int b = blockIdx.x;          // 8 * NSL blocks
  const int c = b & 7, s = b >> 3;
  for (int j = threadIdx.x; j < CHB; j += 1024) h[j] = 0;
  __syncthreads();
  const int* arr = (c < 4) ? src : dst;
  const int base = (c & 3) * CHB;
  const int e0 = s * SLE;
  for (int i = threadIdx.x; i < SLE; i += 1024) {
    int v = arr[e0 + i] - base;
    if ((unsigned)v < CHB) atomicAdd(&h[v], 1);
  }
  __syncthreads();
  int* Pc = P + (size_t)(c * NSL + s) * CHB;
  for (int j = threadIdx.x; j < CHB; j += 1024) Pc[j] = h[j];
}

// ---------------- phase B: reduce -> norms; in-place exclusive scan of in-partials ----------------
__global__ __launch_bounds__(256) void hist_reduce(int* __restrict__ P,
                                                   float* __restrict__ onorm,
                                                   float* __restrict__ inorm,
                                                   int* __restrict__ icnt) {
  int n = blockIdx.x * 256 + threadIdx.x;
  if (n >= 4 * CHB) return;
  const int c = n >> 14, j = n & (CHB - 1);
  // out-degree
  int* Po = P + (size_t)(c * NSL) * CHB + j;
  int od = 0;
#pragma unroll
  for (int s = 0; s < NSL; ++s) od += Po[(size_t)s * CHB];
  // in-degree: exclusive prefix over slices (leaves per-slice cursor bases in P)
  int* Pi = P + (size_t)((4 + c) * NSL) * CHB + j;
  int run = 0;
#pragma unroll
  for (int s = 0; s < NSL; ++s) { int t = Pi[(size_t)s * CHB]; Pi[(size_t)s * CHB] = run; run += t; }
  if (n < NN) {
    onorm[n] = 1.0f / sqrtf(fmaxf((float)od, 1.0f));
    inorm[n] = 1.0f / sqrtf(fmaxf((float)run, 1.0f));
    icnt[n] = run;
  }
}

// ---------------- CSR row scan (int counts) ----------------
__global__ __launch_bounds__(1024) void scan_rows(const int* __restrict__ icnt,
                                                  int* __restrict__ rowstart) {
  __shared__ int wsum[16];
  __shared__ int carry_s;
  const int tid = threadIdx.x, lane = tid & 63, w = tid >> 6;
  if (tid == 0) { carry_s = 0; rowstart[0] = 0; }
  __syncthreads();
  for (int base = 0; base < NN; base += 8192) {
    int i0 = base + tid * 8;
    int c[8];
    int v = 0;
#pragma unroll
    for (int j = 0; j < 8; ++j) {
      int i = i0 + j;
      c[j] = (i < NN) ? icnt[i] : 0;
      v += c[j];
    }
    int inc = v;
#pragma unroll
    for (int off = 1; off < 64; off <<= 1) {
      int t = __shfl_up(inc, off, 64);
      if (lane >= off) inc += t;
    }
    if (lane == 63) wsum[w] = inc;
    __syncthreads();
    int woff = 0;
    for (int k = 0; k < w; ++k) woff += wsum[k];
    int carry = carry_s;
    int run = carry + woff + inc - v;
#pragma unroll
    for (int j = 0; j < 8; ++j) {
      int i = i0 + j;
      if (i < NN) rowstart[i + 1] = run + c[j];
      run += c[j];
    }
    __syncthreads();
    if (tid == 1023) carry_s = carry + woff + inc;
    __syncthreads();
  }
}

// ---------------- CSR fill via LDS cursors (no global atomics) ----------------
__global__ __launch_bounds__(1024) void fill_csr2(const int* __restrict__ src,
                                                  const int* __restrict__ dst,
                                                  const float* __restrict__ onorm,
                                                  const int* __restrict__ rowstart,
                                                  const int* __restrict__ P,
                                                  int* __restrict__ col,
                                                  float* __restrict__ ewt) {
  __shared__ int cur[CHB];
  const int b = blockIdx.x;          // 4 * NSL blocks
  const int c = b & 3, s = b >> 2;
  const int base = c * CHB;
  const int* Pi = P + (size_t)((4 + c) * NSL + s) * CHB;
  for (int j = threadIdx.x; j < CHB; j += 1024) {
    int n = base + j;
    cur[j] = (n < NN ? rowstart[n] : 0) + Pi[j];
  }
  __syncthreads();
  const int e0 = s * SLE;
  for (int i = threadIdx.x; i < SLE; i += 1024) {
    int d = dst[e0 + i] - base;
    if ((unsigned)d < CHB) {
      int sv = src[e0 + i];
      int pos = atomicAdd(&cur[d], 1);   // LDS atomic: fast
      col[pos] = sv;
      ewt[pos] = onorm[sv];
    }
  }
}

// ---------------- gather aggregation (bf16 in -> bf16 out), 8-edge unroll ----------------
__global__ __launch_bounds__(256) void gather_agg(const short* __restrict__ xB,
                                                  const int* __restrict__ rowstart,
                                                  const int* __restrict__ col,
                                                  const float* __restrict__ ewt,
                                                  const float* __restrict__ inorm,
                                                  short* __restrict__ aggB) {
  const int wid = blockIdx.x * 4 + (threadIdx.x >> 6);
  const int lane = threadIdx.x & 63;
  if (wid >= NN) return;
  const int e1 = rowstart[wid + 1];
  int e = rowstart[wid];
  const int fo = lane * 4;
  float a[4] = {0.f, 0.f, 0.f, 0.f};
  for (; e + 8 <= e1; e += 8) {
    int ss[8]; float ww[8]; uint2 uu[8];
#pragma unroll
    for (int q = 0; q < 8; ++q) { ss[q] = col[e + q]; ww[q] = ewt[e + q]; }
#pragma unroll
    for (int q = 0; q < 8; ++q) uu[q] = *(const uint2*)(xB + (size_t)ss[q] * HID + fo);
#pragma unroll
    for (int q = 0; q < 8; ++q) {
      a[0] = fmaf(bf2f((unsigned short)(uu[q].x & 0xFFFF)), ww[q], a[0]);
      a[1] = fmaf(bf2f((unsigned short)(uu[q].x >> 16)),    ww[q], a[1]);
      a[2] = fmaf(bf2f((unsigned short)(uu[q].y & 0xFFFF)), ww[q], a[2]);
      a[3] = fmaf(bf2f((unsigned short)(uu[q].y >> 16)),    ww[q], a[3]);
    }
  }
  for (; e + 2 <= e1; e += 2) {
    int s0 = col[e], s1 = col[e + 1];
    float w0 = ewt[e], w1 = ewt[e + 1];
    uint2 u0 = *(const uint2*)(xB + (size_t)s0 * HID + fo);
    uint2 u1 = *(const uint2*)(xB + (size_t)s1 * HID + fo);
    a[0] = fmaf(bf2f((unsigned short)(u0.x & 0xFFFF)), w0, a[0]);
    a[1] = fmaf(bf2f((unsigned short)(u0.x >> 16)),    w0, a[1]);
    a[2] = fmaf(bf2f((unsigned short)(u0.y & 0xFFFF)), w0, a[2]);
    a[3] = fmaf(bf2f((unsigned short)(u0.y >> 16)),    w0, a[3]);
    a[0] = fmaf(bf2f((unsigned short)(u1.x & 0xFFFF)), w1, a[0]);
    a[1] = fmaf(bf2f((unsigned short)(u1.x >> 16)),    w1, a[1]);
    a[2] = fmaf(bf2f((unsigned short)(u1.y & 0xFFFF)), w1, a[2]);
    a[3] = fmaf(bf2f((unsigned short)(u1.y >> 16)),    w1, a[3]);
  }
  if (e < e1) {
    int s0 = col[e];
    float w0 = ewt[e];
    uint2 u0 = *(const uint2*)(xB + (size_t)s0 * HID + fo);
    a[0] = fmaf(bf2f((unsigned short)(u0.x & 0xFFFF)), w0, a[0]);
    a[1] = fmaf(bf2f((unsigned short)(u0.x >> 16)),    w0, a[1]);
    a[2] = fmaf(bf2f((unsigned short)(u0.y & 0xFFFF)), w0, a[2]);
    a[3] = fmaf(bf2f((unsigned short)(u0.y >> 16)),    w0, a[3]);
  }
  const float wi = inorm[wid];
  unsigned int lo = (unsigned int)f2bf(a[0] * wi) | ((unsigned int)f2bf(a[1] * wi) << 16);
  unsigned int hi = (unsigned int)f2bf(a[2] * wi) | ((unsigned int)f2bf(a[3] * wi) << 16);
  *(uint2*)(aggB + (size_t)wid * HID + fo) = make_uint2(lo, hi);
}

// ---------------- fused weight prep ----------------
__global__ __launch_bounds__(256) void wprep(const float* __restrict__ W1,
                                             const float* __restrict__ W2,
                                             const float* __restrict__ W_ih,
                                             const float* __restrict__ W_hh,
                                             const float* __restrict__ t,
                                             const float* __restrict__ tw,
                                             const float* __restrict__ tb,
                                             const float* __restrict__ b_ih,
                                             const float* __restrict__ b_hh,
                                             short* __restrict__ W1B,
                                             short* __restrict__ W2B,
                                             short* __restrict__ WgB,
                                             float* __restrict__ cst) {
  const int b = blockIdx.x;
  const int k = threadIdx.x;
  if (b < 256) {
    W1B[b * 256 + k] = (short)f2bf(W1[k * 256 + b]);
    W2B[b * 256 + k] = (short)f2bf(W2[k * 256 + b]);
  } else if (b < 512) {
    int u = b - 256;
    int base = (u >> 4) * 64 + (u & 15);
    float v0 = W_ih[(size_t)u * 384 + k] + W_hh[(size_t)u * 256 + k];
    float v1 = W_ih[(size_t)(256 + u) * 384 + k] + W_hh[(size_t)(256 + u) * 256 + k];
    float v2 = W_ih[(size_t)(512 + u) * 384 + k];
    float v3 = W_hh[(size_t)(512 + u) * 256 + k];
    WgB[(size_t)(base + 0)  * 256 + k] = (short)f2bf(v0);
    WgB[(size_t)(base + 16) * 256 + k] = (short)f2bf(v1);
    WgB[(size_t)(base + 32) * 256 + k] = (short)f2bf(v2);
    WgB[(size_t)(base + 48) * 256 + k] = (short)f2bf(v3);
  } else {
    __shared__ float te[TDIM];
    int u = k;
    if (u < TDIM) te[u] = cosf(t[0] * tw[u] + tb[u]);
    __syncthreads();
    float cr = b_ih[u] + b_hh[u];
    float cz = b_ih[256 + u] + b_hh[256 + u];
    float ci = b_ih[512 + u];
    for (int kk = 0; kk < TDIM; ++kk) {
      float tk = te[kk];
      cr = fmaf(tk, W_ih[(size_t)u * 384 + 256 + kk], cr);
      cz = fmaf(tk, W_ih[(size_t)(256 + u) * 384 + 256 + kk], cz);
      ci = fmaf(tk, W_ih[(size_t)(512 + u) * 384 + 256 + kk], ci);
    }
    cst[u] = cr;
    cst[256 + u] = cz;
    cst[512 + u] = ci;
    cst[768 + u] = b_hh[512 + u];
  }
}

// ---------------- MFMA GEMM v4: global_load_lds staging, XCD-chunked blocks ----------------
template <int CT, bool GRUE, bool DUAL>
__global__ __launch_bounds__(256, 3) void gemm_v4(const short* __restrict__ A,
                                                  const short* __restrict__ B,
                                                  const float* __restrict__ bias,
                                                  const float* __restrict__ cst,
                                                  const short* __restrict__ hHp,
                                                  const short* __restrict__ hLp,
                                                  short* __restrict__ outH,
                                                  short* __restrict__ outL,
                                                  float* __restrict__ outF) {
  __shared__ __align__(16) short As[128 * 32];
  __shared__ __align__(16) short Bs[128 * 32];

  const int nwg = gridDim.x;
  const int xcd = blockIdx.x & 7, jj = blockIdx.x >> 3;
  const int q = nwg >> 3, r = nwg & 7;
  const int lidx = (xcd < r ? xcd * (q + 1) : r * (q + 1) + (xcd - r) * q) + jj;
  const int strip = lidx / CT;
  const int ct = lidx % CT;
  const int row0 = strip * 128;
  const int col0 = ct * 128;

  const int tid = threadIdx.x;
  const int l = tid & 63, wv = tid >> 6;
  const int wm = wv >> 1, wn = wv & 1;
  const int fr = l & 15, fg = l >> 4;

  f32x4 acc[4][4];
#pragma unroll
  for (int i = 0; i < 4; ++i)
#pragma unroll
    for (int j = 0; j < 4; ++j) acc[i][j] = (f32x4)(0.0f);

  for (int k0 = 0; k0 < HID; k0 += 32) {
#pragma unroll
    for (int i = 0; i < 2; ++i) {
      int id = tid + i * 256;
      int row = id >> 2, sp = id & 3;
      int s = (sp - (row >> 1)) & 3;
      int gr = row0 + row;
      gr = gr < NN ? gr : NN - 1;
      GLOAD_LDS16(A + (size_t)gr * HID + k0 + s * 8, As + id * 8);
    }
#pragma unroll
    for (int i = 0; i < 2; ++i) {
      int id = tid + i * 256;
      int row = id >> 2, sp = id & 3;
      int s = (sp - (row >> 1)) & 3;
      GLOAD_LDS16(B + (size_t)(col0 + row) * HID + k0 + s * 8, Bs + id * 8);
    }
    __syncthreads();

    bf16x8 bh[4];
#pragma unroll
    for (int nf = 0; nf < 4; ++nf) {
      int rr = wn * 64 + nf * 16 + fr;
      bh[nf] = *(const bf16x8*)(Bs + rr * 32 + (((fg + (rr >> 1)) & 3) << 3));
    }
#pragma unroll
    for (int mf = 0; mf < 4; ++mf) {
      int rr = wm * 64 + mf * 16 + fr;
      bf16x8 ah = *(const bf16x8*)(As + rr * 32 + (((fg + (rr >> 1)) & 3) << 3));
#pragma unroll
      for (int nf = 0; nf < 4; ++nf)
        acc[mf][nf] = __builtin_amdgcn_mfma_f32_16x16x32_bf16(ah, bh[nf], acc[mf][nf], 0, 0, 0);
    }
    __syncthreads();
  }

  if constexpr (!GRUE) {
#pragma unroll
    for (int mf = 0; mf < 4; ++mf) {
      int rbase = row0 + wm * 64 + mf * 16 + fg * 4;
#pragma unroll
      for (int nf = 0; nf < 4; ++nf) {
        int c = col0 + wn * 64 + nf * 16 + fr;
        float bs = bias[c];
#pragma unroll
        for (int j = 0; j < 4; ++j) {
          int row = rbase + j;
          if (row < NN) {
            float v = fmaxf(acc[mf][nf][j] + bs, 0.0f);
            unsigned short hv_ = f2bf(v);
            size_t off = (size_t)row * HID + c;
            outH[off] = (short)hv_;
            if constexpr (DUAL) outL[off] = (short)f2bf(v - bf2f(hv_));
          }
        }
      }
    }
  } else {
    const int u = (ct * 2 + wn) * 16 + fr;
    const float cr = cst[u], cz = cst[256 + u], ci = cst[512 + u], chn = cst[768 + u];
#pragma unroll
    for (int mf = 0; mf < 4; ++mf) {
      int rbase = row0 + wm * 64 + mf * 16 + fg * 4;
#pragma unroll
      for (int j = 0; j < 4; ++j) {
        int row = rbase + j;
        if (row < NN) {
          float dr = acc[mf][0][j] + cr;
          float dz = acc[mf][1][j] + cz;
          float dn = acc[mf][2][j] + ci;
          float dh = acc[mf][3][j] + chn;
          float rg = 1.0f / (1.0f + __expf(-dr));
          float zg = 1.0f / (1.0f + __expf(-dz));
          float ng = tanhf(dn + rg * dh);
          size_t off = (size_t)row * HID + u;
          float hv = bf2f((unsigned short)hHp[off]) + bf2f((unsigned short)hLp[off]);
          outF[off] = (1.0f - zg) * ng + zg * hv;
        }
      }
    }
  }
}

extern "C" void kernel_launch(void* const* d_in, const int* in_sizes, int n_in,
                              void* d_out, int out_size, void* d_ws, size_t ws_size,
                              hipStream_t stream) {
  const float* hidden = (const float*)d_in[0];
  const float* t      = (const float*)d_in[1];
  const int*   src    = (const int*)d_in[2];
  const int*   dst    = (const int*)d_in[3];
  const float* W1     = (const float*)d_in[4];
  const float* b1     = (const float*)d_in[5];
  const float* W2     = (const float*)d_in[6];
  const float* b2     = (const float*)d_in[7];
  const float* time_w = (const float*)d_in[8];
  const float* time_b = (const float*)d_in[9];
  const float* W_ih   = (const float*)d_in[10];
  const float* W_hh   = (const float*)d_in[11];
  const float* b_ih   = (const float*)d_in[12];
  const float* b_hh   = (const float*)d_in[13];
  float* out = (float*)d_out;

  char* p = (char*)d_ws;
  float* onorm = (float*)p;      p += 50048 * 4;
  float* inorm = (float*)p;      p += 50048 * 4;
  float* cst   = (float*)p;      p += 1024 * 4;
  int* rowstart = (int*)p;       p += 50052 * 4;
  int* icnt     = (int*)p;       p += 50048 * 4;
  int* ecol     = (int*)p;       p += 800000 * 4;
  float* ewt    = (float*)p;     p += 800000 * 4;
  const size_t NFE = (size_t)NN * HID;
  short* Xb   = (short*)p;       p += NFE * 2;
  short* aggB = (short*)p;       p += NFE * 2;
  short* h1B  = (short*)p;       p += NFE * 2;
  short* h2H  = (short*)p;       p += NFE * 2;
  short* h2L  = (short*)p;       p += NFE * 2;
  short* W1B  = (short*)p;       p += 65536 * 2;
  short* W2B  = (short*)p;       p += 65536 * 2;
  short* WgB  = (short*)p;       p += 262144 * 2;
  // partial-histogram workspace aliases h2H (8*NSL*CHB ints = 8.4 MB < 25.6 MB;
  // h2H is only written by layer-2 GEMM, after fill_csr2 has consumed P)
  int* P = (int*)h2H;

  // independent prep first
  cvt_hidden<<<(NN * HID / 4 + 255) / 256, 256, 0, stream>>>(hidden, Xb);
  wprep<<<513, 256, 0, stream>>>(W1, W2, W_ih, W_hh, t, time_w, time_b, b_ih, b_hh,
                                 W1B, W2B, WgB, cst);

  // graph prep: privatized histograms -> norms/prefix -> row scan -> LDS-cursor fill
  hist_part<<<8 * NSL, 1024, 0, stream>>>(src, dst, P);
  hist_reduce<<<(4 * CHB + 255) / 256, 256, 0, stream>>>(P, onorm, inorm, icnt);
  scan_rows<<<1, 1024, 0, stream>>>(icnt, rowstart);
  fill_csr2<<<4 * NSL, 1024, 0, stream>>>(src, dst, onorm, rowstart, P, ecol, ewt);

  const int gather_blocks = (NN + 3) / 4;
  const int strips = (NN + 127) / 128;   // 391

  // layer 1
  gather_agg<<<gather_blocks, 256, 0, stream>>>(Xb, rowstart, ecol, ewt, inorm, aggB);
  gemm_v4<2, false, false><<<strips * 2, 256, 0, stream>>>(aggB, W1B, b1, nullptr, nullptr, nullptr, h1B, nullptr, nullptr);

  // layer 2 (writes hi+lo planes; lo only needed for GRU carry)
  gather_agg<<<gather_blocks, 256, 0, stream>>>(h1B, rowstart, ecol, ewt, inorm, aggB);
  gemm_v4<2, false, true><<<strips * 2, 256, 0, stream>>>(aggB, W2B, b2, nullptr, nullptr, nullptr, h2H, h2L, nullptr);

  // GRU: 8 col-tiles per strip, XCD-chunked so A strip stays in one L2
  gemm_v4<8, true, false><<<strips * 8, 256, 0, stream>>>(h2H, WgB, nullptr, cst, h2H, h2L, nullptr, nullptr, out);
}

// Round 8
// 374.691 us; speedup vs baseline: 5.1292x; 1.0318x over previous
//
#include <hip/hip_runtime.h>
#include <cstdint>
#include <cstddef>

#define NN 50000
#define NE 800000
#define HID 256
#define TDIM 128

#define CHB 16384          // bins per histogram chunk (64 KB LDS)
#define NSL 16             // edge slices
#define SLE (NE / NSL)     // 50000 edges per slice

typedef short bf16x8 __attribute__((ext_vector_type(8)));
typedef float f32x4 __attribute__((ext_vector_type(4)));

#define GLOAD_LDS16(g, l)                                                        \
  __builtin_amdgcn_global_load_lds(                                              \
      (const __attribute__((address_space(1))) unsigned int*)(g),                \
      (__attribute__((address_space(3))) unsigned int*)(l), 16, 0, 0)

__device__ inline unsigned short f2bf(float f) {
  uint32_t u = __builtin_bit_cast(uint32_t, f);
  uint32_t r = u + 0x7FFFu + ((u >> 16) & 1u);
  return (unsigned short)(r >> 16);
}
__device__ inline float bf2f(unsigned short s) {
  uint32_t u = ((uint32_t)s) << 16;
  return __builtin_bit_cast(float, u);
}
__device__ inline float fast_sig(float x) {
  return __builtin_amdgcn_rcpf(1.0f + __expf(-x));
}
__device__ inline float fast_tanh(float x) {
  float xc = fminf(fmaxf(x, -10.0f), 10.0f);
  float e = __expf(2.0f * xc);
  return 1.0f - 2.0f * __builtin_amdgcn_rcpf(e + 1.0f);
}

// ---------------- hidden -> bf16 plane ----------------
__global__ __launch_bounds__(256) void cvt_hidden(const float* __restrict__ x,
                                                  short* __restrict__ xb) {
  int i = blockIdx.x * 256 + threadIdx.x;   // one float4 per thread
  if (i < NN * HID / 4) {
    float4 v = ((const float4*)x)[i];
    unsigned int lo = (unsigned int)f2bf(v.x) | ((unsigned int)f2bf(v.y) << 16);
    unsigned int hi = (unsigned int)f2bf(v.z) | ((unsigned int)f2bf(v.w) << 16);
    ((uint2*)xb)[i] = make_uint2(lo, hi);
  }
}

// ---------------- histogram phase A: LDS-privatized partial counts ----------------
__global__ __launch_bounds__(1024) void hist_part(const int* __restrict__ src,
                                                  const int* __restrict__ dst,
                                                  int* __restrict__ P) {
  __shared__ int h[CHB];
  const int b = blockIdx.x;          // 8 * NSL blocks
  const int c = b & 7, s = b >> 3;
  for (int j = threadIdx.x; j < CHB; j += 1024) h[j] = 0;
  __syncthreads();
  const int* arr = (c < 4) ? src : dst;
  const int base = (c & 3) * CHB;
  const int e0 = s * SLE;
  for (int i = threadIdx.x; i < SLE; i += 1024) {
    int v = arr[e0 + i] - base;
    if ((unsigned)v < CHB) atomicAdd(&h[v], 1);
  }
  __syncthreads();
  int* Pc = P + (size_t)(c * NSL + s) * CHB;
  for (int j = threadIdx.x; j < CHB; j += 1024) Pc[j] = h[j];
}

// ---------------- phase B: reduce -> norms; in-place exclusive scan of in-partials ----------------
__global__ __launch_bounds__(256) void hist_reduce(int* __restrict__ P,
                                                   float* __restrict__ onorm,
                                                   float* __restrict__ inorm,
                                                   int* __restrict__ icnt) {
  int n = blockIdx.x * 256 + threadIdx.x;
  if (n >= 4 * CHB) return;
  const int c = n >> 14, j = n & (CHB - 1);
  int* Po = P + (size_t)(c * NSL) * CHB + j;
  int od = 0;
#pragma unroll
  for (int s = 0; s < NSL; ++s) od += Po[(size_t)s * CHB];
  int* Pi = P + (size_t)((4 + c) * NSL) * CHB + j;
  int run = 0;
#pragma unroll
  for (int s = 0; s < NSL; ++s) { int t = Pi[(size_t)s * CHB]; Pi[(size_t)s * CHB] = run; run += t; }
  if (n < NN) {
    onorm[n] = 1.0f / sqrtf(fmaxf((float)od, 1.0f));
    inorm[n] = 1.0f / sqrtf(fmaxf((float)run, 1.0f));
    icnt[n] = run;
  }
}

// ---------------- CSR row scan (int counts) ----------------
__global__ __launch_bounds__(1024) void scan_rows(const int* __restrict__ icnt,
                                                  int* __restrict__ rowstart) {
  __shared__ int wsum[16];
  __shared__ int carry_s;
  const int tid = threadIdx.x, lane = tid & 63, w = tid >> 6;
  if (tid == 0) { carry_s = 0; rowstart[0] = 0; }
  __syncthreads();
  for (int base = 0; base < NN; base += 8192) {
    int i0 = base + tid * 8;
    int c[8];
    int v = 0;
#pragma unroll
    for (int j = 0; j < 8; ++j) {
      int i = i0 + j;
      c[j] = (i < NN) ? icnt[i] : 0;
      v += c[j];
    }
    int inc = v;
#pragma unroll
    for (int off = 1; off < 64; off <<= 1) {
      int t = __shfl_up(inc, off, 64);
      if (lane >= off) inc += t;
    }
    if (lane == 63) wsum[w] = inc;
    __syncthreads();
    int woff = 0;
    for (int k = 0; k < w; ++k) woff += wsum[k];
    int carry = carry_s;
    int run = carry + woff + inc - v;
#pragma unroll
    for (int j = 0; j < 8; ++j) {
      int i = i0 + j;
      if (i < NN) rowstart[i + 1] = run + c[j];
      run += c[j];
    }
    __syncthreads();
    if (tid == 1023) carry_s = carry + woff + inc;
    __syncthreads();
  }
}

// ---------------- CSR fill via LDS cursors (no global atomics) ----------------
__global__ __launch_bounds__(1024) void fill_csr2(const int* __restrict__ src,
                                                  const int* __restrict__ dst,
                                                  const float* __restrict__ onorm,
                                                  const int* __restrict__ rowstart,
                                                  const int* __restrict__ P,
                                                  int* __restrict__ col,
                                                  float* __restrict__ ewt) {
  __shared__ int cur[CHB];
  const int b = blockIdx.x;          // 4 * NSL blocks
  const int c = b & 3, s = b >> 2;
  const int base = c * CHB;
  const int* Pi = P + (size_t)((4 + c) * NSL + s) * CHB;
  for (int j = threadIdx.x; j < CHB; j += 1024) {
    int n = base + j;
    cur[j] = (n < NN ? rowstart[n] : 0) + Pi[j];
  }
  __syncthreads();
  const int e0 = s * SLE;
  for (int i = threadIdx.x; i < SLE; i += 1024) {
    int d = dst[e0 + i] - base;
    if ((unsigned)d < CHB) {
      int sv = src[e0 + i];
      int pos = atomicAdd(&cur[d], 1);   // LDS atomic: fast
      col[pos] = sv;
      ewt[pos] = onorm[sv];
    }
  }
}

// ---------------- gather aggregation (bf16 in -> bf16 out), 8-edge unroll ----------------
__global__ __launch_bounds__(256) void gather_agg(const short* __restrict__ xB,
                                                  const int* __restrict__ rowstart,
                                                  const int* __restrict__ col,
                                                  const float* __restrict__ ewt,
                                                  const float* __restrict__ inorm,
                                                  short* __restrict__ aggB) {
  const int wid = blockIdx.x * 4 + (threadIdx.x >> 6);
  const int lane = threadIdx.x & 63;
  if (wid >= NN) return;
  const int e1 = rowstart[wid + 1];
  int e = rowstart[wid];
  const int fo = lane * 4;
  float a[4] = {0.f, 0.f, 0.f, 0.f};
  for (; e + 8 <= e1; e += 8) {
    int ss[8]; float ww[8]; uint2 uu[8];
#pragma unroll
    for (int q = 0; q < 8; ++q) { ss[q] = col[e + q]; ww[q] = ewt[e + q]; }
#pragma unroll
    for (int q = 0; q < 8; ++q) uu[q] = *(const uint2*)(xB + (size_t)ss[q] * HID + fo);
#pragma unroll
    for (int q = 0; q < 8; ++q) {
      a[0] = fmaf(bf2f((unsigned short)(uu[q].x & 0xFFFF)), ww[q], a[0]);
      a[1] = fmaf(bf2f((unsigned short)(uu[q].x >> 16)),    ww[q], a[1]);
      a[2] = fmaf(bf2f((unsigned short)(uu[q].y & 0xFFFF)), ww[q], a[2]);
      a[3] = fmaf(bf2f((unsigned short)(uu[q].y >> 16)),    ww[q], a[3]);
    }
  }
  for (; e + 2 <= e1; e += 2) {
    int s0 = col[e], s1 = col[e + 1];
    float w0 = ewt[e], w1 = ewt[e + 1];
    uint2 u0 = *(const uint2*)(xB + (size_t)s0 * HID + fo);
    uint2 u1 = *(const uint2*)(xB + (size_t)s1 * HID + fo);
    a[0] = fmaf(bf2f((unsigned short)(u0.x & 0xFFFF)), w0, a[0]);
    a[1] = fmaf(bf2f((unsigned short)(u0.x >> 16)),    w0, a[1]);
    a[2] = fmaf(bf2f((unsigned short)(u0.y & 0xFFFF)), w0, a[2]);
    a[3] = fmaf(bf2f((unsigned short)(u0.y >> 16)),    w0, a[3]);
    a[0] = fmaf(bf2f((unsigned short)(u1.x & 0xFFFF)), w1, a[0]);
    a[1] = fmaf(bf2f((unsigned short)(u1.x >> 16)),    w1, a[1]);
    a[2] = fmaf(bf2f((unsigned short)(u1.y & 0xFFFF)), w1, a[2]);
    a[3] = fmaf(bf2f((unsigned short)(u1.y >> 16)),    w1, a[3]);
  }
  if (e < e1) {
    int s0 = col[e];
    float w0 = ewt[e];
    uint2 u0 = *(const uint2*)(xB + (size_t)s0 * HID + fo);
    a[0] = fmaf(bf2f((unsigned short)(u0.x & 0xFFFF)), w0, a[0]);
    a[1] = fmaf(bf2f((unsigned short)(u0.x >> 16)),    w0, a[1]);
    a[2] = fmaf(bf2f((unsigned short)(u0.y & 0xFFFF)), w0, a[2]);
    a[3] = fmaf(bf2f((unsigned short)(u0.y >> 16)),    w0, a[3]);
  }
  const float wi = inorm[wid];
  unsigned int lo = (unsigned int)f2bf(a[0] * wi) | ((unsigned int)f2bf(a[1] * wi) << 16);
  unsigned int hi = (unsigned int)f2bf(a[2] * wi) | ((unsigned int)f2bf(a[3] * wi) << 16);
  *(uint2*)(aggB + (size_t)wid * HID + fo) = make_uint2(lo, hi);
}

// ---------------- fused weight prep ----------------
__global__ __launch_bounds__(256) void wprep(const float* __restrict__ W1,
                                             const float* __restrict__ W2,
                                             const float* __restrict__ W_ih,
                                             const float* __restrict__ W_hh,
                                             const float* __restrict__ t,
                                             const float* __restrict__ tw,
                                             const float* __restrict__ tb,
                                             const float* __restrict__ b_ih,
                                             const float* __restrict__ b_hh,
                                             short* __restrict__ W1B,
                                             short* __restrict__ W2B,
                                             short* __restrict__ WgB,
                                             float* __restrict__ cst) {
  const int b = blockIdx.x;
  const int k = threadIdx.x;
  if (b < 256) {
    W1B[b * 256 + k] = (short)f2bf(W1[k * 256 + b]);
    W2B[b * 256 + k] = (short)f2bf(W2[k * 256 + b]);
  } else if (b < 512) {
    int u = b - 256;
    int base = (u >> 4) * 64 + (u & 15);
    float v0 = W_ih[(size_t)u * 384 + k] + W_hh[(size_t)u * 256 + k];
    float v1 = W_ih[(size_t)(256 + u) * 384 + k] + W_hh[(size_t)(256 + u) * 256 + k];
    float v2 = W_ih[(size_t)(512 + u) * 384 + k];
    float v3 = W_hh[(size_t)(512 + u) * 256 + k];
    WgB[(size_t)(base + 0)  * 256 + k] = (short)f2bf(v0);
    WgB[(size_t)(base + 16) * 256 + k] = (short)f2bf(v1);
    WgB[(size_t)(base + 32) * 256 + k] = (short)f2bf(v2);
    WgB[(size_t)(base + 48) * 256 + k] = (short)f2bf(v3);
  } else {
    __shared__ float te[TDIM];
    int u = k;
    if (u < TDIM) te[u] = cosf(t[0] * tw[u] + tb[u]);
    __syncthreads();
    float cr = b_ih[u] + b_hh[u];
    float cz = b_ih[256 + u] + b_hh[256 + u];
    float ci = b_ih[512 + u];
    for (int kk = 0; kk < TDIM; ++kk) {
      float tk = te[kk];
      cr = fmaf(tk, W_ih[(size_t)u * 384 + 256 + kk], cr);
      cz = fmaf(tk, W_ih[(size_t)(256 + u) * 384 + 256 + kk], cz);
      ci = fmaf(tk, W_ih[(size_t)(512 + u) * 384 + 256 + kk], ci);
    }
    cst[u] = cr;
    cst[256 + u] = cz;
    cst[512 + u] = ci;
    cst[768 + u] = b_hh[512 + u];
  }
}

// ---------------- MFMA GEMM v5: double-buffered global_load_lds pipeline ----------------
// Block tile 128x128, 4 waves (2x2), wave tile 64x64. One __syncthreads per k-step:
//   loop t: stage(buf^1, k+32) -> ds_read/MFMA(buf) -> __syncthreads (drains vm+lgkm) -> swap.
// LDS 2x(8KB A + 8KB B) = 32 KB; slot-rotate swizzle via pre-swizzled global source.
template <int CT, bool GRUE, bool DUAL>
__global__ __launch_bounds__(256, 4) void gemm_v5(const short* __restrict__ A,
                                                  const short* __restrict__ B,
                                                  const float* __restrict__ bias,
                                                  const float* __restrict__ cst,
                                                  const short* __restrict__ hHp,
                                                  const short* __restrict__ hLp,
                                                  short* __restrict__ outH,
                                                  short* __restrict__ outL,
                                                  float* __restrict__ outF) {
  __shared__ __align__(16) short As[2][128 * 32];
  __shared__ __align__(16) short Bs[2][128 * 32];

  const int nwg = gridDim.x;
  const int xcd = blockIdx.x & 7, jj = blockIdx.x >> 3;
  const int q = nwg >> 3, r = nwg & 7;
  const int lidx = (xcd < r ? xcd * (q + 1) : r * (q + 1) + (xcd - r) * q) + jj;
  const int strip = lidx / CT;
  const int ct = lidx % CT;
  const int row0 = strip * 128;
  const int col0 = ct * 128;

  const int tid = threadIdx.x;
  const int l = tid & 63, wv = tid >> 6;
  const int wm = wv >> 1, wn = wv & 1;
  const int fr = l & 15, fg = l >> 4;

  // per-thread staging geometry (2 A rows + 2 B rows, 16B each)
  int arow[2], asw[2], brow[2], bsw[2];
#pragma unroll
  for (int i = 0; i < 2; ++i) {
    int id = tid + i * 256;
    int row = id >> 2, sp = id & 3;
    int s = (sp - (row >> 1)) & 3;
    int gr = row0 + row;
    arow[i] = (gr < NN ? gr : NN - 1);
    asw[i] = s;
    brow[i] = col0 + row;
    bsw[i] = s;
  }

  f32x4 acc[4][4];
#pragma unroll
  for (int i = 0; i < 4; ++i)
#pragma unroll
    for (int j = 0; j < 4; ++j) acc[i][j] = (f32x4)(0.0f);

  // prologue: stage k0=0 into buf 0
#pragma unroll
  for (int i = 0; i < 2; ++i) {
    int id = tid + i * 256;
    GLOAD_LDS16(A + (size_t)arow[i] * HID + asw[i] * 8, &As[0][id * 8]);
    GLOAD_LDS16(B + (size_t)brow[i] * HID + bsw[i] * 8, &Bs[0][id * 8]);
  }
  __syncthreads();

#pragma unroll
  for (int t = 0; t < 8; ++t) {
    const int buf = t & 1;
    if (t < 7) {
      const int kn = (t + 1) * 32;
#pragma unroll
      for (int i = 0; i < 2; ++i) {
        int id = tid + i * 256;
        GLOAD_LDS16(A + (size_t)arow[i] * HID + kn + asw[i] * 8, &As[buf ^ 1][id * 8]);
        GLOAD_LDS16(B + (size_t)brow[i] * HID + kn + bsw[i] * 8, &Bs[buf ^ 1][id * 8]);
      }
    }
    bf16x8 bh[4];
#pragma unroll
    for (int nf = 0; nf < 4; ++nf) {
      int rr = wn * 64 + nf * 16 + fr;
      bh[nf] = *(const bf16x8*)(&Bs[buf][rr * 32 + (((fg + (rr >> 1)) & 3) << 3)]);
    }
#pragma unroll
    for (int mf = 0; mf < 4; ++mf) {
      int rr = wm * 64 + mf * 16 + fr;
      bf16x8 ah = *(const bf16x8*)(&As[buf][rr * 32 + (((fg + (rr >> 1)) & 3) << 3)]);
#pragma unroll
      for (int nf = 0; nf < 4; ++nf)
        acc[mf][nf] = __builtin_amdgcn_mfma_f32_16x16x32_bf16(ah, bh[nf], acc[mf][nf], 0, 0, 0);
    }
    __syncthreads();   // drains vmcnt (next-buf stage landed) + lgkmcnt
  }

  if constexpr (!GRUE) {
#pragma unroll
    for (int mf = 0; mf < 4; ++mf) {
      int rbase = row0 + wm * 64 + mf * 16 + fg * 4;
#pragma unroll
      for (int nf = 0; nf < 4; ++nf) {
        int c = col0 + wn * 64 + nf * 16 + fr;
        float bs = bias[c];
#pragma unroll
        for (int j = 0; j < 4; ++j) {
          int row = rbase + j;
          if (row < NN) {
            float v = fmaxf(acc[mf][nf][j] + bs, 0.0f);
            unsigned short hv_ = f2bf(v);
            size_t off = (size_t)row * HID + c;
            outH[off] = (short)hv_;
            if constexpr (DUAL) outL[off] = (short)f2bf(v - bf2f(hv_));
          }
        }
      }
    }
  } else {
    const int u = (ct * 2 + wn) * 16 + fr;
    const float cr = cst[u], cz = cst[256 + u], ci = cst[512 + u], chn = cst[768 + u];
#pragma unroll
    for (int mf = 0; mf < 4; ++mf) {
      int rbase = row0 + wm * 64 + mf * 16 + fg * 4;
#pragma unroll
      for (int j = 0; j < 4; ++j) {
        int row = rbase + j;
        if (row < NN) {
          float dr = acc[mf][0][j] + cr;
          float dz = acc[mf][1][j] + cz;
          float dn = acc[mf][2][j] + ci;
          float dh = acc[mf][3][j] + chn;
          float rg = fast_sig(dr);
          float zg = fast_sig(dz);
          float ng = fast_tanh(dn + rg * dh);
          size_t off = (size_t)row * HID + u;
          float hv = bf2f((unsigned short)hHp[off]) + bf2f((unsigned short)hLp[off]);
          outF[off] = (1.0f - zg) * ng + zg * hv;
        }
      }
    }
  }
}

extern "C" void kernel_launch(void* const* d_in, const int* in_sizes, int n_in,
                              void* d_out, int out_size, void* d_ws, size_t ws_size,
                              hipStream_t stream) {
  const float* hidden = (const float*)d_in[0];
  const float* t      = (const float*)d_in[1];
  const int*   src    = (const int*)d_in[2];
  const int*   dst    = (const int*)d_in[3];
  const float* W1     = (const float*)d_in[4];
  const float* b1     = (const float*)d_in[5];
  const float* W2     = (const float*)d_in[6];
  const float* b2     = (const float*)d_in[7];
  const float* time_w = (const float*)d_in[8];
  const float* time_b = (const float*)d_in[9];
  const float* W_ih   = (const float*)d_in[10];
  const float* W_hh   = (const float*)d_in[11];
  const float* b_ih   = (const float*)d_in[12];
  const float* b_hh   = (const float*)d_in[13];
  float* out = (float*)d_out;

  char* p = (char*)d_ws;
  float* onorm = (float*)p;      p += 50048 * 4;
  float* inorm = (float*)p;      p += 50048 * 4;
  float* cst   = (float*)p;      p += 1024 * 4;
  int* rowstart = (int*)p;       p += 50052 * 4;
  int* icnt     = (int*)p;       p += 50048 * 4;
  int* ecol     = (int*)p;       p += 800000 * 4;
  float* ewt    = (float*)p;     p += 800000 * 4;
  const size_t NFE = (size_t)NN * HID;
  short* Xb   = (short*)p;       p += NFE * 2;
  short* aggB = (short*)p;       p += NFE * 2;
  short* h1B  = (short*)p;       p += NFE * 2;
  short* h2H  = (short*)p;       p += NFE * 2;
  short* h2L  = (short*)p;       p += NFE * 2;
  short* W1B  = (short*)p;       p += 65536 * 2;
  short* W2B  = (short*)p;       p += 65536 * 2;
  short* WgB  = (short*)p;       p += 262144 * 2;
  // partial-histogram workspace aliases h2H (8*NSL*CHB ints = 8.4 MB < 25.6 MB;
  // h2H is only written by layer-2 GEMM, after fill_csr2 has consumed P)
  int* P = (int*)h2H;

  // independent prep first
  cvt_hidden<<<(NN * HID / 4 + 255) / 256, 256, 0, stream>>>(hidden, Xb);
  wprep<<<513, 256, 0, stream>>>(W1, W2, W_ih, W_hh, t, time_w, time_b, b_ih, b_hh,
                                 W1B, W2B, WgB, cst);

  // graph prep: privatized histograms -> norms/prefix -> row scan -> LDS-cursor fill
  hist_part<<<8 * NSL, 1024, 0, stream>>>(src, dst, P);
  hist_reduce<<<(4 * CHB + 255) / 256, 256, 0, stream>>>(P, onorm, inorm, icnt);
  scan_rows<<<1, 1024, 0, stream>>>(icnt, rowstart);
  fill_csr2<<<4 * NSL, 1024, 0, stream>>>(src, dst, onorm, rowstart, P, ecol, ewt);

  const int gather_blocks = (NN + 3) / 4;
  const int strips = (NN + 127) / 128;   // 391

  // layer 1
  gather_agg<<<gather_blocks, 256, 0, stream>>>(Xb, rowstart, ecol, ewt, inorm, aggB);
  gemm_v5<2, false, false><<<strips * 2, 256, 0, stream>>>(aggB, W1B, b1, nullptr, nullptr, nullptr, h1B, nullptr, nullptr);

  // layer 2 (writes hi+lo planes; lo only needed for GRU carry)
  gather_agg<<<gather_blocks, 256, 0, stream>>>(h1B, rowstart, ecol, ewt, inorm, aggB);
  gemm_v5<2, false, true><<<strips * 2, 256, 0, stream>>>(aggB, W2B, b2, nullptr, nullptr, nullptr, h2H, h2L, nullptr);

  // GRU: 8 col-tiles per strip, XCD-chunked so A strip stays in one L2
  gemm_v5<8, true, false><<<strips * 8, 256, 0, stream>>>(h2H, WgB, nullptr, cst, h2H, h2L, nullptr, nullptr, out);
}